// Round 2
// baseline (607.091 us; speedup 1.0000x reference)
//
#include <hip/hip_runtime.h>
#include <hip/hip_bf16.h>
#include <stdint.h>
#include <math.h>

#define NB 256      // graphs (B)
#define NN 256      // nodes at level 0
#define HC 32       // hidden channels
#define EMBD 256    // embedding dim
#define NF 9        // atom feature columns
#define NV 128      // padded vocab

typedef __hip_bfloat16 bf16;

__device__ __forceinline__ float cvt(const bf16 x) { return __bfloat162float(x); }
__device__ __forceinline__ float cvt(const float x) { return x; }
__device__ __forceinline__ void stout(bf16* p, float v) { *p = __float2bfloat16(v); }
__device__ __forceinline__ void stout(float* p, float v) { *p = v; }

// Converted-weight segment offsets (element counts in f32 scratch)
#define OFF_WD0 0        // 8192  w_down0 [256,32]
#define OFF_BD0 8192     // 32    b_down0
#define OFF_WD  8224     // 3072  w_down [3,32,32]
#define OFF_BD  11296    // 96    b_down [3,32]
#define OFF_WP  11392    // 96    w_pool [3,32]
#define OFF_WU  11488    // 2048  w_up [2,32,32]
#define OFF_BU  13536    // 64    b_up [2,32]
#define OFF_WUL 13600    // 8192  w_up_last [32,256]
#define OFF_BUL 21792    // 256   b_up_last
#define OFF_TAB 22048    // 294912 atom_table [9,128,256]
#define W_TOTAL 316960

// ---------------------------------------------------------------------------
// dtype detection: f32 adj words (0.0f / 1.0f) always have zero low-16 bits;
// a bf16 buffer has 0x3F80 in low halves at ~12% density. flag=1 -> float32.
__global__ void k_det(const unsigned int* __restrict__ adjw, int* __restrict__ flag) {
    __shared__ int found;
    int t = threadIdx.x;
    if (t == 0) found = 0;
    __syncthreads();
    int loc = 0;
    for (int i = 0; i < 32; ++i) {
        unsigned int w = adjw[t + 256 * i];
        if (w & 0xFFFFu) loc = 1;
    }
    if (loc) atomicOr(&found, 1);
    __syncthreads();
    if (t == 0) flag[0] = found ? 0 : 1;
}

// ---------------------------------------------------------------------------
// Convert all small weights to f32 scratch (dual dtype via flag).
__global__ void k_cvtw(const void* p0, const void* p1, const void* p2, const void* p3,
                       const void* p4, const void* p5, const void* p6, const void* p7,
                       const void* p8, const void* p9, float* __restrict__ dst,
                       const int* __restrict__ flag) {
    int gid = blockIdx.x * 256 + threadIdx.x;
    if (gid >= W_TOTAL) return;
    bool f32 = flag[0] != 0;
    const void* src; int j;
    if      (gid < OFF_BD0) { src = p0; j = gid - OFF_WD0; }
    else if (gid < OFF_WD)  { src = p1; j = gid - OFF_BD0; }
    else if (gid < OFF_BD)  { src = p2; j = gid - OFF_WD; }
    else if (gid < OFF_WP)  { src = p3; j = gid - OFF_BD; }
    else if (gid < OFF_WU)  { src = p4; j = gid - OFF_WP; }
    else if (gid < OFF_BU)  { src = p5; j = gid - OFF_WU; }
    else if (gid < OFF_WUL) { src = p6; j = gid - OFF_BU; }
    else if (gid < OFF_BUL) { src = p7; j = gid - OFF_WUL; }
    else if (gid < OFF_TAB) { src = p8; j = gid - OFF_BUL; }
    else                    { src = p9; j = gid - OFF_TAB; }
    dst[gid] = f32 ? ((const float*)src)[j] : cvt(((const bf16*)src)[j]);
}

// ---------------------------------------------------------------------------
// TW[f,v,c] = sum_e table[f,v,e] * W0[e,c]   (both f32 from scratch)
__global__ void k_tw(const float* __restrict__ table, const float* __restrict__ W0,
                     float* __restrict__ TW) {
    int gid = blockIdx.x * 256 + threadIdx.x;
    if (gid >= NF * NV * HC) return;
    int c = gid & 31;
    int v = (gid >> 5) & (NV - 1);
    int f = gid >> 12;
    const float* trow = table + (size_t)(f * NV + v) * EMBD;
    float acc = 0.f;
    for (int e = 0; e < EMBD; ++e) acc += trow[e] * W0[e * HC + c];
    TW[gid] = acc;
}

// ---------------------------------------------------------------------------
// di[b,j] = 1/sqrt(2 + colsum(A))  (A symmetric -> colsum == rowsum, coalesced)
template <typename T>
__global__ void k_deg(const T* __restrict__ A, float* __restrict__ di, int n,
                      const int* __restrict__ flag, int want) {
    if (flag && flag[0] != want) return;
    int b = blockIdx.x, t = threadIdx.x;
    if (t >= n) return;
    const T* Ab = A + (size_t)b * n * n;
    float acc = 0.f;
    for (int i = 0; i < n; ++i) acc += cvt(Ab[(size_t)i * n + t]);
    di[b * n + t] = 1.0f / sqrtf(acc + 2.0f);
}

// ---------------------------------------------------------------------------
// z0[b,n,c] = di0[b,n] * sum_f TW[f, x_atom[b,n,f], c]   (= di0 * (h @ W0))
__global__ void k_y0(const int* __restrict__ xa, const float* __restrict__ TW,
                     const float* __restrict__ di0, float* __restrict__ z0) {
    int gid = blockIdx.x * 256 + threadIdx.x;  // B*N*HC
    int c = gid & 31;
    int node = gid >> 5;
    const int* xrow = xa + node * NF;
    float acc = 0.f;
#pragma unroll
    for (int f = 0; f < NF; ++f) {
        int v = xrow[f];
        acc += TW[(f * NV + v) * HC + c];
    }
    z0[gid] = acc * di0[node];
}

// ---------------------------------------------------------------------------
// GCN core: xout[b,r,c] = act( di[r]*( sum_j A[r,j]*z[j,c] + 2*z[r,c] ) + bias[c] )
// z = di * (x @ W) precomputed. One block = 32 rows of one graph.
template <typename T, int RELU>
__global__ void __launch_bounds__(256) k_az(const T* __restrict__ A,
                                            const float* __restrict__ z,
                                            const float* __restrict__ di,
                                            const float* __restrict__ bias,
                                            float* __restrict__ xout, int n,
                                            const int* __restrict__ flag, int want) {
    if (flag && flag[0] != want) return;
    __shared__ __align__(16) float zl[256 * 36];
    __shared__ float dil[256];
    int tiles = n >> 5;
    int b = blockIdx.x / tiles;
    int tile = blockIdx.x % tiles;
    int t = threadIdx.x;
    for (int idx = t; idx < n * HC; idx += 256) {
        int j = idx >> 5, c = idx & 31;
        zl[j * 36 + c] = z[((size_t)b * n + j) * HC + c];
    }
    for (int idx = t; idx < n; idx += 256) dil[idx] = di[b * n + idx];
    __syncthreads();
    int r0 = t >> 3;
    int cq = (t & 7) * 4;
    int r = tile * 32 + r0;
    const T* arow = A + ((size_t)b * n + r) * n;
    float a0 = 0.f, a1 = 0.f, a2 = 0.f, a3 = 0.f;
    for (int j = 0; j < n; ++j) {
        float a = cvt(arow[j]);
        const float4 zv = *reinterpret_cast<const float4*>(&zl[j * 36 + cq]);
        a0 += a * zv.x; a1 += a * zv.y; a2 += a * zv.z; a3 += a * zv.w;
    }
    float dr = dil[r];
    float o0 = dr * (a0 + 2.f * zl[r * 36 + cq + 0]) + bias[cq + 0];
    float o1 = dr * (a1 + 2.f * zl[r * 36 + cq + 1]) + bias[cq + 1];
    float o2 = dr * (a2 + 2.f * zl[r * 36 + cq + 2]) + bias[cq + 2];
    float o3 = dr * (a3 + 2.f * zl[r * 36 + cq + 3]) + bias[cq + 3];
    if (RELU) {
        o0 = fmaxf(o0, 0.f); o1 = fmaxf(o1, 0.f);
        o2 = fmaxf(o2, 0.f); o3 = fmaxf(o3, 0.f);
    }
    float4 res = make_float4(o0, o1, o2, o3);
    *reinterpret_cast<float4*>(&xout[((size_t)b * n + r) * HC + cq]) = res;
}

// ---------------------------------------------------------------------------
// Top-k: score = tanh(x.w/||w||); bitonic sort (desc score, asc index ties).
__global__ void k_topk(const float* __restrict__ x, const float* __restrict__ w,
                       int n, int k, int* __restrict__ idxo, float* __restrict__ valso) {
    __shared__ float wl[HC];
    __shared__ float sc[256];
    __shared__ unsigned long long keys[256];
    __shared__ float snorm;
    int b = blockIdx.x, t = threadIdx.x;
    if (t < HC) wl[t] = w[t];
    __syncthreads();
    if (t == 0) {
        float s = 0.f;
        for (int i = 0; i < HC; ++i) s += wl[i] * wl[i];
        snorm = sqrtf(s);
    }
    __syncthreads();
    const float* xr = x + ((size_t)b * n + t) * HC;
    float acc = 0.f;
    for (int c = 0; c < HC; ++c) acc += xr[c] * wl[c];
    float s = tanhf(acc / snorm);
    sc[t] = s;
    unsigned int bits = __float_as_uint(s);
    unsigned int m = ((int)bits < 0) ? 0xFFFFFFFFu : 0x80000000u;
    unsigned int ordv = ~(bits ^ m);
    keys[t] = ((unsigned long long)ordv << 32) | (unsigned int)t;
    __syncthreads();
    for (int size = 2; size <= n; size <<= 1) {
        for (int stride = size >> 1; stride > 0; stride >>= 1) {
            int j = t ^ stride;
            if (j > t) {
                bool asc = ((t & size) == 0);
                unsigned long long ka = keys[t], kb = keys[j];
                if ((ka > kb) == asc) { keys[t] = kb; keys[j] = ka; }
            }
            __syncthreads();
        }
    }
    if (t < k) {
        int id = (int)(keys[t] & 0xFFFFFFFFu);
        idxo[b * k + t] = id;
        valso[b * k + t] = sc[id];
    }
}

// ---------------------------------------------------------------------------
// Fused augment + gather:
// out[b,r,s] = <A1[i_r,:], A1[i_s,:]>, A1 = A + I (A symmetric, zero diag); diag out = 0.
template <typename T>
__global__ void __launch_bounds__(256) k_auggather(const T* __restrict__ A,
                                                   const int* __restrict__ idx,
                                                   float* __restrict__ out, int n, int k,
                                                   const int* __restrict__ flag, int want) {
    if (flag && flag[0] != want) return;
    __shared__ float Rl[32 * 260];
    __shared__ __align__(16) float SlT[256 * 36];
    int tiles = k >> 5;
    int bx = blockIdx.x;
    int b = bx / (tiles * tiles);
    int rem = bx % (tiles * tiles);
    int rt = rem / tiles, st = rem % tiles;
    int t = threadIdx.x;
    const int* idxb = idx + b * k;
    const T* Ab = A + (size_t)b * n * n;
    for (int a = 0; a < 32; ++a) {
        int row = idxb[rt * 32 + a];
        for (int j = t; j < n; j += 256) {
            float v = cvt(Ab[(size_t)row * n + j]);
            if (j == row) v += 1.0f;
            Rl[a * 260 + j] = v;
        }
    }
    for (int a = 0; a < 32; ++a) {
        int row = idxb[st * 32 + a];
        for (int j = t; j < n; j += 256) {
            float v = cvt(Ab[(size_t)row * n + j]);
            if (j == row) v += 1.0f;
            SlT[j * 36 + a] = v;
        }
    }
    __syncthreads();
    int r0 = t >> 3, s4 = (t & 7) * 4;
    float a0 = 0.f, a1 = 0.f, a2 = 0.f, a3 = 0.f;
    for (int j = 0; j < n; ++j) {
        float br = Rl[r0 * 260 + j];
        const float4 sv = *reinterpret_cast<const float4*>(&SlT[j * 36 + s4]);
        a0 += br * sv.x; a1 += br * sv.y; a2 += br * sv.z; a3 += br * sv.w;
    }
    int gr = rt * 32 + r0;
    int gsb = st * 32 + s4;
    float vq0 = (gr == gsb + 0) ? 0.f : a0;
    float vq1 = (gr == gsb + 1) ? 0.f : a1;
    float vq2 = (gr == gsb + 2) ? 0.f : a2;
    float vq3 = (gr == gsb + 3) ? 0.f : a3;
    float* op = &out[((size_t)b * k + gr) * k + gsb];
    op[0] = vq0; op[1] = vq1; op[2] = vq2; op[3] = vq3;
}

// ---------------------------------------------------------------------------
// z[b,r,c] = di[b,r] * scale * sum_e x[b,row,e] * W[e,c]
__global__ void k_xw(const float* __restrict__ xin, int nin, int nout,
                     const int* __restrict__ idx, const float* __restrict__ vals,
                     const float* __restrict__ W, const float* __restrict__ di,
                     float* __restrict__ zout) {
    __shared__ float Wl[HC * 33];
    int t = threadIdx.x;
    for (int i = t; i < HC * HC; i += 256) Wl[(i >> 5) * 33 + (i & 31)] = W[i];
    __syncthreads();
    int gid = blockIdx.x * 256 + t;
    int c = gid & 31;
    int rr = gid >> 5;
    int r = rr % nout;
    int b = rr / nout;
    int row = idx ? idx[b * nout + r] : r;
    float scale = vals ? vals[b * nout + r] : 1.0f;
    const float* xr = xin + ((size_t)b * nin + row) * HC;
    float acc = 0.f;
    for (int e = 0; e < HC; ++e) acc += xr[e] * Wl[e * 33 + c];
    zout[gid] = di[b * nout + r] * scale * acc;
}

// ---------------------------------------------------------------------------
__global__ void k_copy(const float* __restrict__ src, float* __restrict__ dst, int total) {
    int gid = blockIdx.x * 256 + threadIdx.x;
    if (gid < total) dst[gid] = src[gid];
}

__global__ void k_scatter(float* __restrict__ dst, const int* __restrict__ idx,
                          const float* __restrict__ xsrc, int n, int k) {
    int gid = blockIdx.x * 256 + threadIdx.x;  // B*k*HC
    int c = gid & 31;
    int rr = gid >> 5;
    int r = rr % k;
    int b = rr / k;
    int j = idx[b * k + r];
    dst[((size_t)b * n + j) * HC + c] += xsrc[gid];
}

// ---------------------------------------------------------------------------
// Final GCN (32->256) fused with global_add_pool:
// out[b,e] = sum_c g[c]*W[c,e] + 256*bias[e], g[c] = sum_j s[j]*x[b,j,c],
// s[j] = di0[j]*( sum_i adj[i,j]*di0[i] + 2*di0[j] )
template <typename T>
__global__ void __launch_bounds__(256) k_final(const T* __restrict__ adj,
                                               const float* __restrict__ di0,
                                               const float* __restrict__ xin,
                                               const float* __restrict__ Wul,
                                               const float* __restrict__ bul,
                                               T* __restrict__ outp,
                                               const int* __restrict__ flag, int want) {
    if (flag && flag[0] != want) return;
    __shared__ float dil[NN];
    __shared__ float sarr[NN];
    __shared__ float part[8 * 33];
    __shared__ float gl[HC];
    int b = blockIdx.x, t = threadIdx.x;
    dil[t] = di0[b * NN + t];
    __syncthreads();
    const T* Ab = adj + (size_t)b * NN * NN;
    float acc = 0.f;
    for (int i = 0; i < NN; ++i) acc += cvt(Ab[(size_t)i * NN + t]) * dil[i];
    sarr[t] = dil[t] * (acc + 2.f * dil[t]);
    __syncthreads();
    int c = t & 31, jg = t >> 5;
    float a2 = 0.f;
    for (int j = jg * 32; j < jg * 32 + 32; ++j)
        a2 += sarr[j] * xin[((size_t)b * NN + j) * HC + c];
    part[jg * 33 + c] = a2;
    __syncthreads();
    if (t < HC) {
        float g = 0.f;
        for (int q = 0; q < 8; ++q) g += part[q * 33 + t];
        gl[t] = g;
    }
    __syncthreads();
    float a3 = 0.f;
    for (int cc = 0; cc < HC; ++cc) a3 += gl[cc] * Wul[cc * EMBD + t];
    stout(&outp[b * EMBD + t], a3 + 256.0f * bul[t]);
}

// ---------------------------------------------------------------------------
extern "C" void kernel_launch(void* const* d_in, const int* in_sizes, int n_in,
                              void* d_out, int out_size, void* d_ws, size_t ws_size,
                              hipStream_t stream) {
    const void* adj       = d_in[0];
    const int*  xatom     = (const int*)d_in[1];

    float* ws = (float*)d_ws;
    size_t off = 0;
    auto alloc = [&](size_t nf) {
        float* p = ws + off;
        off += (nf + 63) & ~((size_t)63);
        return p;
    };
    int*   flag  = (int*)alloc(64);
    float* wsW   = alloc(W_TOTAL);
    float* TW    = alloc(NF * NV * HC);
    float* di0   = alloc(NB * NN);
    float* z0    = alloc((size_t)NB * NN * HC);
    float* x0    = alloc((size_t)NB * NN * HC);
    float* Ag0   = alloc((size_t)NB * 128 * 128);
    float* di1   = alloc(NB * 128);
    float* x1    = alloc((size_t)NB * 128 * HC);
    float* Ag1   = alloc((size_t)NB * 64 * 64);
    float* di2   = alloc(NB * 64);
    float* x2    = alloc((size_t)NB * 64 * HC);
    float* Ag2   = alloc((size_t)NB * 32 * 32);
    float* di3   = alloc(NB * 32);
    float* x3    = alloc((size_t)NB * 32 * HC);
    float* zbuf  = alloc((size_t)NB * 128 * HC);
    float* mbuf  = alloc((size_t)NB * NN * HC);
    float* decx  = alloc((size_t)NB * 128 * HC);
    float* vals0 = alloc(NB * 128);
    float* vals1 = alloc(NB * 64);
    float* vals2 = alloc(NB * 32);
    int* idx0 = (int*)alloc(NB * 128);
    int* idx1 = (int*)alloc(NB * 64);
    int* idx2 = (int*)alloc(NB * 32);

    const float* adjF = (const float*)adj;
    const bf16*  adjB = (const bf16*)adj;
    float* outF = (float*)d_out;
    bf16*  outB = (bf16*)d_out;

    // dtype detection + weight conversion to f32 scratch
    k_det<<<1, 256, 0, stream>>>((const unsigned int*)adj, flag);
    k_cvtw<<<(W_TOTAL + 255) / 256, 256, 0, stream>>>(
        d_in[3], d_in[4], d_in[5], d_in[6], d_in[7], d_in[8], d_in[9], d_in[10],
        d_in[11], d_in[2], wsW, flag);

    // Encoder entry
    k_tw<<<(NF * NV * HC + 255) / 256, 256, 0, stream>>>(wsW + OFF_TAB, wsW + OFF_WD0, TW);
    k_deg<float><<<NB, NN, 0, stream>>>(adjF, di0, NN, flag, 1);
    k_deg<bf16><<<NB, NN, 0, stream>>>(adjB, di0, NN, flag, 0);
    k_y0<<<(NB * NN * HC) / 256, 256, 0, stream>>>(xatom, TW, di0, z0);
    k_az<float, 1><<<NB * (NN / 32), 256, 0, stream>>>(adjF, z0, di0, wsW + OFF_BD0, x0, NN, flag, 1);
    k_az<bf16, 1><<<NB * (NN / 32), 256, 0, stream>>>(adjB, z0, di0, wsW + OFF_BD0, x0, NN, flag, 0);

    // Level 0 pool: 256 -> 128
    k_topk<<<NB, 256, 0, stream>>>(x0, wsW + OFF_WP + 0, 256, 128, idx0, vals0);
    k_auggather<float><<<NB * 16, 256, 0, stream>>>(adjF, idx0, Ag0, 256, 128, flag, 1);
    k_auggather<bf16><<<NB * 16, 256, 0, stream>>>(adjB, idx0, Ag0, 256, 128, flag, 0);
    k_deg<float><<<NB, 128, 0, stream>>>(Ag0, di1, 128, nullptr, 0);
    k_xw<<<(NB * 128 * HC) / 256, 256, 0, stream>>>(x0, 256, 128, idx0, vals0, wsW + OFF_WD + 0, di1, zbuf);
    k_az<float, 1><<<NB * 4, 256, 0, stream>>>(Ag0, zbuf, di1, wsW + OFF_BD + 0, x1, 128, nullptr, 0);

    // Level 1 pool: 128 -> 64
    k_topk<<<NB, 128, 0, stream>>>(x1, wsW + OFF_WP + 32, 128, 64, idx1, vals1);
    k_auggather<float><<<NB * 4, 256, 0, stream>>>(Ag0, idx1, Ag1, 128, 64, nullptr, 0);
    k_deg<float><<<NB, 64, 0, stream>>>(Ag1, di2, 64, nullptr, 0);
    k_xw<<<(NB * 64 * HC) / 256, 256, 0, stream>>>(x1, 128, 64, idx1, vals1, wsW + OFF_WD + 1024, di2, zbuf);
    k_az<float, 1><<<NB * 2, 256, 0, stream>>>(Ag1, zbuf, di2, wsW + OFF_BD + 32, x2, 64, nullptr, 0);

    // Level 2 pool: 64 -> 32
    k_topk<<<NB, 64, 0, stream>>>(x2, wsW + OFF_WP + 64, 64, 32, idx2, vals2);
    k_auggather<float><<<NB, 256, 0, stream>>>(Ag1, idx2, Ag2, 64, 32, nullptr, 0);
    k_deg<float><<<NB, 32, 0, stream>>>(Ag2, di3, 32, nullptr, 0);
    k_xw<<<(NB * 32 * HC) / 256, 256, 0, stream>>>(x2, 64, 32, idx2, vals2, wsW + OFF_WD + 2048, di3, zbuf);
    k_az<float, 1><<<NB, 256, 0, stream>>>(Ag2, zbuf, di3, wsW + OFF_BD + 64, x3, 32, nullptr, 0);

    // Decode step 0 (32 -> 64)
    k_copy<<<(NB * 64 * HC) / 256, 256, 0, stream>>>(x2, mbuf, NB * 64 * HC);
    k_scatter<<<(NB * 32 * HC) / 256, 256, 0, stream>>>(mbuf, idx2, x3, 64, 32);
    k_xw<<<(NB * 64 * HC) / 256, 256, 0, stream>>>(mbuf, 64, 64, nullptr, nullptr, wsW + OFF_WU + 0, di2, zbuf);
    k_az<float, 1><<<NB * 2, 256, 0, stream>>>(Ag1, zbuf, di2, wsW + OFF_BU + 0, decx, 64, nullptr, 0);

    // Decode step 1 (64 -> 128)
    k_copy<<<(NB * 128 * HC) / 256, 256, 0, stream>>>(x1, mbuf, NB * 128 * HC);
    k_scatter<<<(NB * 64 * HC) / 256, 256, 0, stream>>>(mbuf, idx1, decx, 128, 64);
    k_xw<<<(NB * 128 * HC) / 256, 256, 0, stream>>>(mbuf, 128, 128, nullptr, nullptr, wsW + OFF_WU + 1024, di1, zbuf);
    k_az<float, 1><<<NB * 4, 256, 0, stream>>>(Ag0, zbuf, di1, wsW + OFF_BU + 32, decx, 128, nullptr, 0);

    // Decode step 2 (128 -> 256) + final GCN + global_add_pool
    k_copy<<<(NB * NN * HC) / 256, 256, 0, stream>>>(x0, mbuf, NB * NN * HC);
    k_scatter<<<(NB * 128 * HC) / 256, 256, 0, stream>>>(mbuf, idx0, decx, 256, 128);
    k_final<float><<<NB, 256, 0, stream>>>(adjF, di0, mbuf, wsW + OFF_WUL, wsW + OFF_BUL, outF, flag, 1);
    k_final<bf16><<<NB, 256, 0, stream>>>(adjB, di0, mbuf, wsW + OFF_WUL, wsW + OFF_BUL, outB, flag, 0);
}

// Round 3
// 287.709 us; speedup vs baseline: 2.1101x; 2.1101x over previous
//
#include <hip/hip_runtime.h>
#include <stdint.h>
#include <math.h>

#define NB 256      // graphs (B)
#define NN 256      // nodes at level 0
#define HC 32       // hidden channels
#define EMBD 256    // embedding dim
#define NF 9        // atom feature columns
#define NV 128      // padded vocab

typedef unsigned int u32;
typedef unsigned long long u64;

// ---------------------------------------------------------------------------
// Bitpack adjacency (exactly 0/1 f32) + fused degree -> di0 = 1/sqrt(deg+2).
// One wave per row; 4 ballot passes of 64 coalesced floats.
__global__ void __launch_bounds__(256) k_pack(const float* __restrict__ A,
                                              u32* __restrict__ packed,
                                              float* __restrict__ di0) {
    int t = threadIdx.x;
    int wave = t >> 6, lane = t & 63;
    int b = blockIdx.x >> 6;
    int row = ((blockIdx.x & 63) << 2) + wave;
    const float* ar = A + ((size_t)b * NN + row) * NN;
    u32* pr = packed + ((size_t)b * NN + row) * 8;
    int deg = 0;
#pragma unroll
    for (int p = 0; p < 4; ++p) {
        float v = ar[p * 64 + lane];
        u64 m = __ballot(v != 0.0f);
        if (lane == 0) {
            pr[2 * p]     = (u32)m;
            pr[2 * p + 1] = (u32)(m >> 32);
            deg += __popcll(m);
        }
    }
    if (lane == 0) di0[b * NN + row] = 1.0f / sqrtf((float)deg + 2.0f);
}

// ---------------------------------------------------------------------------
// TW[f,v,c] = sum_e table[f,v,e] * W0[e,c]
__global__ void k_tw(const float* __restrict__ table, const float* __restrict__ W0,
                     float* __restrict__ TW) {
    int gid = blockIdx.x * 256 + threadIdx.x;
    if (gid >= NF * NV * HC) return;
    int c = gid & 31;
    int v = (gid >> 5) & (NV - 1);
    int f = gid >> 12;
    const float* trow = table + (size_t)(f * NV + v) * EMBD;
    float acc = 0.f;
    for (int e = 0; e < EMBD; ++e) acc += trow[e] * W0[e * HC + c];
    TW[gid] = acc;
}

// ---------------------------------------------------------------------------
// z0[b,n,c] = di0[b,n] * sum_f TW[f, x_atom[b,n,f], c]
__global__ void k_y0(const int* __restrict__ xa, const float* __restrict__ TW,
                     const float* __restrict__ di0, float* __restrict__ z0) {
    int gid = blockIdx.x * 256 + threadIdx.x;  // B*N*HC
    int c = gid & 31;
    int node = gid >> 5;
    const int* xrow = xa + node * NF;
    float acc = 0.f;
#pragma unroll
    for (int f = 0; f < NF; ++f) {
        int v = xrow[f];
        acc += TW[(f * NV + v) * HC + c];
    }
    z0[gid] = acc * di0[node];
}

// ---------------------------------------------------------------------------
// Level-0 GCN neighbor sum via sparse bit iteration (avg degree ~16).
// xout[b,r,c] = relu( di[r]*( sum_{j in N(r)} z[j,c] + 2 z[r,c] ) + bias[c] )
__global__ void __launch_bounds__(256) k_az0p(const u32* __restrict__ packed,
                                              const float* __restrict__ z,
                                              const float* __restrict__ di,
                                              const float* __restrict__ bias,
                                              float* __restrict__ xout) {
    __shared__ __align__(16) float zl[NN * 36];
    __shared__ float dil[NN];
    __shared__ u32 pw[32 * 8];
    int b = blockIdx.x >> 3, tile = blockIdx.x & 7, t = threadIdx.x;
    for (int idx = t; idx < NN * HC; idx += 256) {
        int j = idx >> 5, c = idx & 31;
        zl[j * 36 + c] = z[((size_t)b * NN + j) * HC + c];
    }
    dil[t] = di[b * NN + t];
    pw[t] = packed[((size_t)b * NN + tile * 32) * 8 + t];
    __syncthreads();
    int r0 = t >> 3, cq = (t & 7) * 4;
    int r = tile * 32 + r0;
    float a0 = 0.f, a1 = 0.f, a2 = 0.f, a3 = 0.f;
#pragma unroll
    for (int w = 0; w < 8; ++w) {
        u32 m = pw[r0 * 8 + w];
        int base = w * 32;
        while (m) {
            int j = base + __ffs(m) - 1;
            m &= m - 1;
            const float4 zv = *reinterpret_cast<const float4*>(&zl[j * 36 + cq]);
            a0 += zv.x; a1 += zv.y; a2 += zv.z; a3 += zv.w;
        }
    }
    float dr = dil[r];
    float o0 = dr * (a0 + 2.f * zl[r * 36 + cq + 0]) + bias[cq + 0];
    float o1 = dr * (a1 + 2.f * zl[r * 36 + cq + 1]) + bias[cq + 1];
    float o2 = dr * (a2 + 2.f * zl[r * 36 + cq + 2]) + bias[cq + 2];
    float o3 = dr * (a3 + 2.f * zl[r * 36 + cq + 3]) + bias[cq + 3];
    o0 = fmaxf(o0, 0.f); o1 = fmaxf(o1, 0.f);
    o2 = fmaxf(o2, 0.f); o3 = fmaxf(o3, 0.f);
    *reinterpret_cast<float4*>(&xout[((size_t)b * NN + r) * HC + cq]) =
        make_float4(o0, o1, o2, o3);
}

// ---------------------------------------------------------------------------
// Top-k + inverse permutation. Block = n threads.
__global__ void k_topk(const float* __restrict__ x, const float* __restrict__ w,
                       int n, int k, int* __restrict__ idxo, float* __restrict__ valso,
                       int* __restrict__ invo) {
    __shared__ float wl[HC];
    __shared__ float sc[256];
    __shared__ unsigned long long keys[256];
    __shared__ float snorm;
    int b = blockIdx.x, t = threadIdx.x;
    invo[b * n + t] = -1;
    if (t < HC) wl[t] = w[t];
    __syncthreads();
    if (t == 0) {
        float s = 0.f;
        for (int i = 0; i < HC; ++i) s += wl[i] * wl[i];
        snorm = sqrtf(s);
    }
    __syncthreads();
    const float* xr = x + ((size_t)b * n + t) * HC;
    float acc = 0.f;
    for (int c = 0; c < HC; ++c) acc += xr[c] * wl[c];
    float s = tanhf(acc / snorm);
    sc[t] = s;
    unsigned int bits = __float_as_uint(s);
    unsigned int m = ((int)bits < 0) ? 0xFFFFFFFFu : 0x80000000u;
    unsigned int ordv = ~(bits ^ m);
    keys[t] = ((unsigned long long)ordv << 32) | (unsigned int)t;
    __syncthreads();
    for (int size = 2; size <= n; size <<= 1) {
        for (int stride = size >> 1; stride > 0; stride >>= 1) {
            int j = t ^ stride;
            if (j > t) {
                bool asc = ((t & size) == 0);
                unsigned long long ka = keys[t], kb = keys[j];
                if ((ka > kb) == asc) { keys[t] = kb; keys[j] = ka; }
            }
            __syncthreads();
        }
    }
    if (t < k) {
        int id = (int)(keys[t] & 0xFFFFFFFFu);
        idxo[b * k + t] = id;
        valso[b * k + t] = sc[id];
        invo[b * n + id] = t;
    }
}

// ---------------------------------------------------------------------------
// Level-0 augment+gather via popcount:
// out[b,r,s] = popc(P1_r & P1_s), P1 = packed gathered row with diag bit set;
// diag of out forced 0. Exact integer arithmetic. One block = 32 r-rows.
__global__ void __launch_bounds__(256) k_aggpop(const u32* __restrict__ packed,
                                                const int* __restrict__ idx,
                                                float* __restrict__ out) {
    __shared__ u32 P[128 * 9];
    __shared__ int idl[128];
    int b = blockIdx.x >> 2, rt = blockIdx.x & 3, t = threadIdx.x;
    if (t < 128) idl[t] = idx[b * 128 + t];
    __syncthreads();
    for (int i = t; i < 128 * 8; i += 256) {
        int r = i >> 3, w = i & 7;
        int row = idl[r];
        u32 word = packed[((size_t)b * NN + row) * 8 + w];
        if (w == (row >> 5)) word |= (1u << (row & 31));
        P[r * 9 + w] = word;
    }
    __syncthreads();
    int r0 = t >> 3, r = rt * 32 + r0;
    int sb = (t & 7) * 4;
    u32 rw[8];
#pragma unroll
    for (int w = 0; w < 8; ++w) rw[w] = P[r * 9 + w];
#pragma unroll
    for (int k4 = 0; k4 < 4; ++k4) {
        float4 res;
        float* rp = &res.x;
#pragma unroll
        for (int j = 0; j < 4; ++j) {
            int s = sb + 32 * k4 + j;
            int cnt = 0;
#pragma unroll
            for (int w = 0; w < 8; ++w) cnt += __popc(rw[w] & P[s * 9 + w]);
            rp[j] = (s == r) ? 0.f : (float)cnt;
        }
        *reinterpret_cast<float4*>(&out[((size_t)b * 128 + r) * 128 + sb + 32 * k4]) = res;
    }
}

// ---------------------------------------------------------------------------
// di[b,j] = 1/sqrt(2 + colsum(A))  (A symmetric -> coalesced). Block = n.
__global__ void k_deg(const float* __restrict__ A, float* __restrict__ di, int n) {
    int b = blockIdx.x, t = threadIdx.x;
    const float* Ab = A + (size_t)b * n * n;
    float acc = 0.f;
    for (int i = 0; i < n; ++i) acc += Ab[(size_t)i * n + t];
    di[b * n + t] = 1.0f / sqrtf(acc + 2.0f);
}

// ---------------------------------------------------------------------------
// Dense augment+gather (non-0/1 A): out[b,r,s] = <A1[i_r,:],A1[i_s,:]>, diag 0.
template <int NMAX>
__global__ void __launch_bounds__(256) k_auggather(const float* __restrict__ A,
                                                   const int* __restrict__ idx,
                                                   float* __restrict__ out, int n, int k) {
    __shared__ float Rl[32 * (NMAX + 4)];
    __shared__ __align__(16) float SlT[NMAX * 36];
    int tiles = k >> 5;
    int bx = blockIdx.x;
    int b = bx / (tiles * tiles);
    int rem = bx % (tiles * tiles);
    int rt = rem / tiles, st = rem % tiles;
    int t = threadIdx.x;
    const int* idxb = idx + b * k;
    const float* Ab = A + (size_t)b * n * n;
    for (int a = 0; a < 32; ++a) {
        int row = idxb[rt * 32 + a];
        for (int j = t; j < n; j += 256) {
            float v = Ab[(size_t)row * n + j];
            if (j == row) v += 1.0f;
            Rl[a * (NMAX + 4) + j] = v;
        }
    }
    for (int a = 0; a < 32; ++a) {
        int row = idxb[st * 32 + a];
        for (int j = t; j < n; j += 256) {
            float v = Ab[(size_t)row * n + j];
            if (j == row) v += 1.0f;
            SlT[j * 36 + a] = v;
        }
    }
    __syncthreads();
    int r0 = t >> 3, s4 = (t & 7) * 4;
    float a0 = 0.f, a1 = 0.f, a2 = 0.f, a3 = 0.f;
    for (int j = 0; j < n; ++j) {
        float br = Rl[r0 * (NMAX + 4) + j];
        const float4 sv = *reinterpret_cast<const float4*>(&SlT[j * 36 + s4]);
        a0 += br * sv.x; a1 += br * sv.y; a2 += br * sv.z; a3 += br * sv.w;
    }
    int gr = rt * 32 + r0;
    int gsb = st * 32 + s4;
    float vq0 = (gr == gsb + 0) ? 0.f : a0;
    float vq1 = (gr == gsb + 1) ? 0.f : a1;
    float vq2 = (gr == gsb + 2) ? 0.f : a2;
    float vq3 = (gr == gsb + 3) ? 0.f : a3;
    float* op = &out[((size_t)b * k + gr) * k + gsb];
    op[0] = vq0; op[1] = vq1; op[2] = vq2; op[3] = vq3;
}

// ---------------------------------------------------------------------------
// z[b,r,c] = di[b,r] * scale * sum_e xval[e] * W[e,c]
// encoder: row = idx[b,r], scale = vals[b,r]
// decoder: xval[e] = xin[b,r,e] + (inv[b,r]>=0 ? xup[b,inv[b,r],e] : 0)
__global__ void k_xw(const float* __restrict__ xin, int nin, int nout,
                     const int* __restrict__ idx, const float* __restrict__ vals,
                     const int* __restrict__ inv, const float* __restrict__ xup, int kup,
                     const float* __restrict__ W, const float* __restrict__ di,
                     float* __restrict__ zout) {
    __shared__ float Wl[HC * 33];
    int t = threadIdx.x;
    for (int i = t; i < HC * HC; i += 256) Wl[(i >> 5) * 33 + (i & 31)] = W[i];
    __syncthreads();
    int gid = blockIdx.x * 256 + t;
    int c = gid & 31;
    int rr = gid >> 5;
    int r = rr % nout;
    int b = rr / nout;
    int row = idx ? idx[b * nout + r] : r;
    float scale = vals ? vals[b * nout + r] : 1.0f;
    const float* xr = xin + ((size_t)b * nin + row) * HC;
    const float* ur = nullptr;
    if (inv) {
        int ir = inv[b * nin + r];
        if (ir >= 0) ur = xup + ((size_t)b * kup + ir) * HC;
    }
    float acc = 0.f;
    for (int e = 0; e < HC; ++e) {
        float xv = xr[e];
        if (ur) xv += ur[e];
        acc += xv * Wl[e * 33 + c];
    }
    zout[gid] = di[b * nout + r] * scale * acc;
}

// ---------------------------------------------------------------------------
// Dense GCN core (relu): xout[b,r,c] = relu(di[r]*(sum_j A[r,j] z[j,c] + 2 z[r,c]) + b[c])
template <int NMAX>
__global__ void __launch_bounds__(256) k_az(const float* __restrict__ A,
                                            const float* __restrict__ z,
                                            const float* __restrict__ di,
                                            const float* __restrict__ bias,
                                            float* __restrict__ xout, int n) {
    __shared__ __align__(16) float zl[NMAX * 36];
    __shared__ float dil[NMAX];
    int tiles = n >> 5;
    int b = blockIdx.x / tiles;
    int tile = blockIdx.x % tiles;
    int t = threadIdx.x;
    for (int idx = t; idx < n * HC; idx += 256) {
        int j = idx >> 5, c = idx & 31;
        zl[j * 36 + c] = z[((size_t)b * n + j) * HC + c];
    }
    for (int idx = t; idx < n; idx += 256) dil[idx] = di[b * n + idx];
    __syncthreads();
    int r0 = t >> 3;
    int cq = (t & 7) * 4;
    int r = tile * 32 + r0;
    const float* arow = A + ((size_t)b * n + r) * n;
    float a0 = 0.f, a1 = 0.f, a2 = 0.f, a3 = 0.f;
    for (int j = 0; j < n; ++j) {
        float a = arow[j];
        const float4 zv = *reinterpret_cast<const float4*>(&zl[j * 36 + cq]);
        a0 += a * zv.x; a1 += a * zv.y; a2 += a * zv.z; a3 += a * zv.w;
    }
    float dr = dil[r];
    float o0 = fmaxf(dr * (a0 + 2.f * zl[r * 36 + cq + 0]) + bias[cq + 0], 0.f);
    float o1 = fmaxf(dr * (a1 + 2.f * zl[r * 36 + cq + 1]) + bias[cq + 1], 0.f);
    float o2 = fmaxf(dr * (a2 + 2.f * zl[r * 36 + cq + 2]) + bias[cq + 2], 0.f);
    float o3 = fmaxf(dr * (a3 + 2.f * zl[r * 36 + cq + 3]) + bias[cq + 3], 0.f);
    *reinterpret_cast<float4*>(&xout[((size_t)b * n + r) * HC + cq]) =
        make_float4(o0, o1, o2, o3);
}

// ---------------------------------------------------------------------------
// Final: merge(x0, decx via inv0) -> GCN(32->256, packed adj) -> global_add_pool.
// out[b,e] = (sum_j s[j] x[j,:]) W[:,e] + 256*bias[e],
// s[j] = di0[j]*( sum_{i in N(j)} di0[i] + 2 di0[j] )
__global__ void __launch_bounds__(256) k_final(const u32* __restrict__ packed,
                                               const float* __restrict__ di0,
                                               const float* __restrict__ x0,
                                               const int* __restrict__ inv0,
                                               const float* __restrict__ xup,
                                               const float* __restrict__ Wul,
                                               const float* __restrict__ bul,
                                               float* __restrict__ outp) {
    __shared__ float dil[NN];
    __shared__ float sarr[NN];
    __shared__ int invl[NN];
    __shared__ float part[8 * 33];
    __shared__ float gl[HC];
    int b = blockIdx.x, t = threadIdx.x;
    dil[t] = di0[b * NN + t];
    invl[t] = inv0[b * NN + t];
    __syncthreads();
    const u32* pr = packed + ((size_t)b * NN + t) * 8;
    float acc = 0.f;
#pragma unroll
    for (int w = 0; w < 8; ++w) {
        u32 m = pr[w];
        int base = w * 32;
        while (m) {
            int i = base + __ffs(m) - 1;
            m &= m - 1;
            acc += dil[i];
        }
    }
    sarr[t] = dil[t] * (acc + 2.f * dil[t]);
    __syncthreads();
    int c = t & 31, jg = t >> 5;
    float a2 = 0.f;
    for (int j = jg * 32; j < jg * 32 + 32; ++j) {
        int ir = invl[j];
        float xv = x0[((size_t)b * NN + j) * HC + c];
        if (ir >= 0) xv += xup[((size_t)b * 128 + ir) * HC + c];
        a2 += sarr[j] * xv;
    }
    part[jg * 33 + c] = a2;
    __syncthreads();
    if (t < HC) {
        float g = 0.f;
        for (int q = 0; q < 8; ++q) g += part[q * 33 + t];
        gl[t] = g;
    }
    __syncthreads();
    float a3 = 0.f;
    for (int cc = 0; cc < HC; ++cc) a3 += gl[cc] * Wul[cc * EMBD + t];
    outp[b * EMBD + t] = a3 + 256.0f * bul[t];
}

// ---------------------------------------------------------------------------
extern "C" void kernel_launch(void* const* d_in, const int* in_sizes, int n_in,
                              void* d_out, int out_size, void* d_ws, size_t ws_size,
                              hipStream_t stream) {
    const float* adj       = (const float*)d_in[0];
    const int*   xatom     = (const int*)d_in[1];
    const float* table     = (const float*)d_in[2];
    const float* w_down0   = (const float*)d_in[3];
    const float* b_down0   = (const float*)d_in[4];
    const float* w_down    = (const float*)d_in[5];
    const float* b_down    = (const float*)d_in[6];
    const float* w_pool    = (const float*)d_in[7];
    const float* w_up      = (const float*)d_in[8];
    const float* b_up      = (const float*)d_in[9];
    const float* w_up_last = (const float*)d_in[10];
    const float* b_up_last = (const float*)d_in[11];
    float* outp = (float*)d_out;

    float* ws = (float*)d_ws;
    size_t off = 0;
    auto alloc = [&](size_t nf) {
        float* p = ws + off;
        off += (nf + 63) & ~((size_t)63);
        return p;
    };
    u32*   packed = (u32*)alloc((size_t)NB * NN * 8);
    float* TW    = alloc(NF * NV * HC);
    float* di0   = alloc(NB * NN);
    float* z0    = alloc((size_t)NB * NN * HC);
    float* x0    = alloc((size_t)NB * NN * HC);
    float* Ag0   = alloc((size_t)NB * 128 * 128);
    float* di1   = alloc(NB * 128);
    float* x1    = alloc((size_t)NB * 128 * HC);
    float* Ag1   = alloc((size_t)NB * 64 * 64);
    float* di2   = alloc(NB * 64);
    float* x2    = alloc((size_t)NB * 64 * HC);
    float* Ag2   = alloc((size_t)NB * 32 * 32);
    float* di3   = alloc(NB * 32);
    float* x3    = alloc((size_t)NB * 32 * HC);
    float* zbuf  = alloc((size_t)NB * 128 * HC);
    float* decx  = alloc((size_t)NB * 128 * HC);
    float* vals0 = alloc(NB * 128);
    float* vals1 = alloc(NB * 64);
    float* vals2 = alloc(NB * 32);
    int* idx0 = (int*)alloc(NB * 128);
    int* idx1 = (int*)alloc(NB * 64);
    int* idx2 = (int*)alloc(NB * 32);
    int* inv0 = (int*)alloc(NB * 256);
    int* inv1 = (int*)alloc(NB * 128);
    int* inv2 = (int*)alloc(NB * 64);

    // Pack adjacency + di0
    k_pack<<<NB * 64, 256, 0, stream>>>(adj, packed, di0);

    // Encoder entry
    k_tw<<<(NF * NV * HC + 255) / 256, 256, 0, stream>>>(table, w_down0, TW);
    k_y0<<<(NB * NN * HC) / 256, 256, 0, stream>>>(xatom, TW, di0, z0);
    k_az0p<<<NB * 8, 256, 0, stream>>>(packed, z0, di0, b_down0, x0);

    // Level 0 pool: 256 -> 128
    k_topk<<<NB, 256, 0, stream>>>(x0, w_pool + 0, 256, 128, idx0, vals0, inv0);
    k_aggpop<<<NB * 4, 256, 0, stream>>>(packed, idx0, Ag0);
    k_deg<<<NB, 128, 0, stream>>>(Ag0, di1, 128);
    k_xw<<<(NB * 128 * HC) / 256, 256, 0, stream>>>(x0, 256, 128, idx0, vals0,
                                                    nullptr, nullptr, 0, w_down + 0, di1, zbuf);
    k_az<128><<<NB * 4, 256, 0, stream>>>(Ag0, zbuf, di1, b_down + 0, x1, 128);

    // Level 1 pool: 128 -> 64
    k_topk<<<NB, 128, 0, stream>>>(x1, w_pool + 32, 128, 64, idx1, vals1, inv1);
    k_auggather<128><<<NB * 4, 256, 0, stream>>>(Ag0, idx1, Ag1, 128, 64);
    k_deg<<<NB, 64, 0, stream>>>(Ag1, di2, 64);
    k_xw<<<(NB * 64 * HC) / 256, 256, 0, stream>>>(x1, 128, 64, idx1, vals1,
                                                   nullptr, nullptr, 0, w_down + 1024, di2, zbuf);
    k_az<64><<<NB * 2, 256, 0, stream>>>(Ag1, zbuf, di2, b_down + 32, x2, 64);

    // Level 2 pool: 64 -> 32
    k_topk<<<NB, 64, 0, stream>>>(x2, w_pool + 64, 64, 32, idx2, vals2, inv2);
    k_auggather<64><<<NB, 256, 0, stream>>>(Ag1, idx2, Ag2, 64, 32);
    k_deg<<<NB, 32, 0, stream>>>(Ag2, di3, 32);
    k_xw<<<(NB * 32 * HC) / 256, 256, 0, stream>>>(x2, 64, 32, idx2, vals2,
                                                   nullptr, nullptr, 0, w_down + 2048, di3, zbuf);
    k_az<32><<<NB, 256, 0, stream>>>(Ag2, zbuf, di3, b_down + 64, x3, 32);

    // Decode step 0 (32 -> 64): merge(x2, x3 via inv2) -> GCN on Ag1
    k_xw<<<(NB * 64 * HC) / 256, 256, 0, stream>>>(x2, 64, 64, nullptr, nullptr,
                                                   inv2, x3, 32, w_up + 0, di2, zbuf);
    k_az<64><<<NB * 2, 256, 0, stream>>>(Ag1, zbuf, di2, b_up + 0, decx, 64);

    // Decode step 1 (64 -> 128): merge(x1, decx via inv1) -> GCN on Ag0
    k_xw<<<(NB * 128 * HC) / 256, 256, 0, stream>>>(x1, 128, 128, nullptr, nullptr,
                                                    inv1, decx, 64, w_up + 1024, di1, zbuf);
    k_az<128><<<NB * 4, 256, 0, stream>>>(Ag0, zbuf, di1, b_up + 32, decx, 128);

    // Decode step 2 (128 -> 256): merge(x0, decx via inv0) -> final GCN + pool
    k_final<<<NB, 256, 0, stream>>>(packed, di0, x0, inv0, decx, w_up_last, b_up_last, outp);
}

// Round 4
// 170.982 us; speedup vs baseline: 3.5506x; 1.6827x over previous
//
#include <hip/hip_runtime.h>
#include <stdint.h>
#include <math.h>

#define NB 256      // graphs (B)
#define NN 256      // nodes at level 0
#define HC 32       // hidden channels
#define EMBD 256    // embedding dim
#define NF 9        // atom feature columns
#define NV 128      // padded vocab

typedef unsigned int u32;
typedef unsigned long long u64;

// ---------------------------------------------------------------------------
// Bitpack adjacency (exactly 0/1 f32) + fused degree -> di0 = 1/sqrt(deg+2).
__global__ void __launch_bounds__(256) k_pack(const float* __restrict__ A,
                                              u32* __restrict__ packed,
                                              float* __restrict__ di0) {
    int t = threadIdx.x;
    int wave = t >> 6, lane = t & 63;
    int b = blockIdx.x >> 6;
    int row = ((blockIdx.x & 63) << 2) + wave;
    const float* ar = A + ((size_t)b * NN + row) * NN;
    u32* pr = packed + ((size_t)b * NN + row) * 8;
    int deg = 0;
#pragma unroll
    for (int p = 0; p < 4; ++p) {
        float v = ar[p * 64 + lane];
        u64 m = __ballot(v != 0.0f);
        if (lane == 0) {
            pr[2 * p]     = (u32)m;
            pr[2 * p + 1] = (u32)(m >> 32);
            deg += __popcll(m);
        }
    }
    if (lane == 0) di0[b * NN + row] = 1.0f / sqrtf((float)deg + 2.0f);
}

// ---------------------------------------------------------------------------
// TW[f,v,c] = sum_e table[f,v,e] * W0[e,c]
__global__ void k_tw(const float* __restrict__ table, const float* __restrict__ W0,
                     float* __restrict__ TW) {
    int gid = blockIdx.x * 256 + threadIdx.x;
    if (gid >= NF * NV * HC) return;
    int c = gid & 31;
    int v = (gid >> 5) & (NV - 1);
    int f = gid >> 12;
    const float* trow = table + (size_t)(f * NV + v) * EMBD;
    float acc = 0.f;
    for (int e = 0; e < EMBD; ++e) acc += trow[e] * W0[e * HC + c];
    TW[gid] = acc;
}

// ---------------------------------------------------------------------------
// LDS layout (byte offsets inside one 256-thread block; total 155680 <= 160K)
#define SM_BITS   0        // u32[2048]   adjacency bits
#define SM_DI0    8192     // f[256]
#define SM_BIG0   9216     // f[16384]    z0 (stride36) -> Ag0[128][128]
#define SM_X1     74752    // f[4096]     x1[128][32]
#define SM_BIG1   91136    // f[4096]     xg0 -> Ag1[64][64] -> dec128[128][32]
#define SM_X2     107520   // f[2048]     x2[64][32]
#define SM_BIG2   115712   // f[2048]     Ag2[1024]+x3[1024] -> dec64[64][32]
#define SM_ZB     123904   // f[4608]     z (stride 36) + xg sub-areas
#define SM_WL     142336   // 4608B       Pg u32[128*9] / Wl f[32*33]
#define SM_SC     146944   // f[256]      scores / sarr
#define SM_KEYS   147968   // u64[256]
#define SM_IDX0   150016   // i[128]
#define SM_VALS0  150528   // f[128]
#define SM_INV0   151040   // i[256]
#define SM_IDX1   152064   // i[64]
#define SM_VALS1  152320   // f[64]
#define SM_INV1   152576   // i[128]
#define SM_IDX2   153088   // i[32]
#define SM_VALS2  153216   // f[32]
#define SM_INV2   153344   // i[64]
#define SM_DI1    153600   // f[128]
#define SM_DI2    154112   // f[64]
#define SM_DI3    154368   // f[32]
#define SM_PART   154496   // f[264]
#define SM_GL     155552   // f[32]
#define SM_TOTAL  155680

// Bitonic top-k over scores sc[0..N) -> idx/vals[0..K), inv[0..N).
template <int N, int K>
__device__ __forceinline__ void topk_sort(const float* sc, u64* keys,
                                          int* idxo, float* valso, int* invo, int t) {
    if (t < N) {
        invo[t] = -1;
        float s = sc[t];
        u32 bits = __float_as_uint(s);
        u32 m = ((int)bits < 0) ? 0xFFFFFFFFu : 0x80000000u;
        u32 ordv = ~(bits ^ m);
        keys[t] = ((u64)ordv << 32) | (u32)t;
    }
    __syncthreads();
    for (int size = 2; size <= N; size <<= 1)
        for (int stride = size >> 1; stride > 0; stride >>= 1) {
            if (t < N) {
                int j = t ^ stride;
                if (j > t) {
                    bool asc = ((t & size) == 0);
                    u64 ka = keys[t], kb = keys[j];
                    if ((ka > kb) == asc) { keys[t] = kb; keys[j] = ka; }
                }
            }
            __syncthreads();
        }
    if (t < K) {
        int id = (int)(keys[t] & 0xFFFFFFFFu);
        idxo[t] = id;
        valso[t] = sc[id];
        invo[id] = t;
    }
    __syncthreads();
}

// Dense GCN core on LDS: xout[r,c] = relu?( di[r]*(sum_j A[r,j] z[j,c] + 2 z[r,c]) + bias[c] )
// z has row stride 36; lane rotation on j to spread LDS banks.
template <int N>
__device__ __forceinline__ void az_dense(const float* A, const float* z,
                                         const float* di, const float* bias,
                                         float* xout, int t) {
    int r0 = t >> 3, cq = (t & 7) * 4;
    for (int tile = 0; tile < N / 32; ++tile) {
        int r = tile * 32 + r0;
        float a0 = 0.f, a1 = 0.f, a2 = 0.f, a3 = 0.f;
        for (int jj = 0; jj < N; ++jj) {
            int j = (jj + r0) & (N - 1);
            float a = A[r * N + j];
            const float4 zv = *reinterpret_cast<const float4*>(&z[j * 36 + cq]);
            a0 += a * zv.x; a1 += a * zv.y; a2 += a * zv.z; a3 += a * zv.w;
        }
        float dr = di[r];
        float o0 = fmaxf(dr * (a0 + 2.f * z[r * 36 + cq + 0]) + bias[cq + 0], 0.f);
        float o1 = fmaxf(dr * (a1 + 2.f * z[r * 36 + cq + 1]) + bias[cq + 1], 0.f);
        float o2 = fmaxf(dr * (a2 + 2.f * z[r * 36 + cq + 2]) + bias[cq + 2], 0.f);
        float o3 = fmaxf(dr * (a3 + 2.f * z[r * 36 + cq + 3]) + bias[cq + 3], 0.f);
        *reinterpret_cast<float4*>(&xout[r * 32 + cq]) = make_float4(o0, o1, o2, o3);
    }
    __syncthreads();
}

// Gathered augment: Agout[r,s] = <A1[i_r],A1[i_s]> = dot(A[i_r],A[i_s]) + 2A[i_r,i_s] + d_rs; diag 0.
// N = source dim, K = out dim. float4 dots with lane rotation.
template <int N, int K>
__device__ __forceinline__ void aug_dense(const float* A, const int* idxl,
                                          float* Agout, int t) {
    int rr0 = t >> 3, sb = (t & 7) * 4;
    for (int rt = 0; rt < K / 32; ++rt) {
        int r = rt * 32 + rr0;
        int ir = idxl[r];
        for (int k4 = 0; k4 < K / 32; ++k4) {
            int s0 = sb + 32 * k4;
            int is0 = idxl[s0], is1 = idxl[s0 + 1], is2 = idxl[s0 + 2], is3 = idxl[s0 + 3];
            float c0 = 0.f, c1 = 0.f, c2 = 0.f, c3 = 0.f;
            for (int jj = 0; jj < N / 4; ++jj) {
                int jq = (jj + rr0) & (N / 4 - 1);
                const float4 ar = *reinterpret_cast<const float4*>(&A[ir * N + jq * 4]);
                const float4 s0v = *reinterpret_cast<const float4*>(&A[is0 * N + jq * 4]);
                const float4 s1v = *reinterpret_cast<const float4*>(&A[is1 * N + jq * 4]);
                const float4 s2v = *reinterpret_cast<const float4*>(&A[is2 * N + jq * 4]);
                const float4 s3v = *reinterpret_cast<const float4*>(&A[is3 * N + jq * 4]);
                c0 += ar.x * s0v.x + ar.y * s0v.y + ar.z * s0v.z + ar.w * s0v.w;
                c1 += ar.x * s1v.x + ar.y * s1v.y + ar.z * s1v.z + ar.w * s1v.w;
                c2 += ar.x * s2v.x + ar.y * s2v.y + ar.z * s2v.z + ar.w * s2v.w;
                c3 += ar.x * s3v.x + ar.y * s3v.y + ar.z * s3v.z + ar.w * s3v.w;
            }
            float v0 = c0 + 2.f * A[ir * N + is0] + (ir == is0 ? 1.f : 0.f);
            float v1 = c1 + 2.f * A[ir * N + is1] + (ir == is1 ? 1.f : 0.f);
            float v2 = c2 + 2.f * A[ir * N + is2] + (ir == is2 ? 1.f : 0.f);
            float v3 = c3 + 2.f * A[ir * N + is3] + (ir == is3 ? 1.f : 0.f);
            if (r == s0 + 0) v0 = 0.f;
            if (r == s0 + 1) v1 = 0.f;
            if (r == s0 + 2) v2 = 0.f;
            if (r == s0 + 3) v3 = 0.f;
            *reinterpret_cast<float4*>(&Agout[r * K + s0]) = make_float4(v0, v1, v2, v3);
        }
    }
    __syncthreads();
}

// col-degree of LDS matrix (symmetric) -> di = 1/sqrt(sum+2)
template <int N>
__device__ __forceinline__ void deg_lds(const float* A, float* di, int t) {
    if (t < N) {
        float acc = 0.f;
        for (int i = 0; i < N; ++i) acc += A[i * N + t];
        di[t] = 1.0f / sqrtf(acc + 2.0f);
    }
    __syncthreads();
}

// ---------------------------------------------------------------------------
__global__ void __launch_bounds__(256, 1) k_mega(
    const u32* __restrict__ packed, const float* __restrict__ di0g,
    const float* __restrict__ TW, const int* __restrict__ xa,
    const float* __restrict__ bd0, const float* __restrict__ wd,
    const float* __restrict__ bd, const float* __restrict__ wp,
    const float* __restrict__ wu, const float* __restrict__ bu,
    const float* __restrict__ wul, const float* __restrict__ bul,
    float* __restrict__ gx0, float* __restrict__ outp) {
    __shared__ __align__(16) char SM[SM_TOTAL];
    u32* bitsl   = (u32*)(SM + SM_BITS);
    float* di0l  = (float*)(SM + SM_DI0);
    float* big0  = (float*)(SM + SM_BIG0);
    float* x1l   = (float*)(SM + SM_X1);
    float* big1  = (float*)(SM + SM_BIG1);
    float* x2l   = (float*)(SM + SM_X2);
    float* big2  = (float*)(SM + SM_BIG2);
    float* zb    = (float*)(SM + SM_ZB);
    u32*   Pg    = (u32*)(SM + SM_WL);
    float* Wl    = (float*)(SM + SM_WL);
    float* scl   = (float*)(SM + SM_SC);
    u64*   keys  = (u64*)(SM + SM_KEYS);
    int*   idx0l = (int*)(SM + SM_IDX0);
    float* vals0l= (float*)(SM + SM_VALS0);
    int*   inv0l = (int*)(SM + SM_INV0);
    int*   idx1l = (int*)(SM + SM_IDX1);
    float* vals1l= (float*)(SM + SM_VALS1);
    int*   inv1l = (int*)(SM + SM_INV1);
    int*   idx2l = (int*)(SM + SM_IDX2);
    float* vals2l= (float*)(SM + SM_VALS2);
    int*   inv2l = (int*)(SM + SM_INV2);
    float* di1   = (float*)(SM + SM_DI1);
    float* di2   = (float*)(SM + SM_DI2);
    float* di3   = (float*)(SM + SM_DI3);
    float* part  = (float*)(SM + SM_PART);
    float* gl    = (float*)(SM + SM_GL);
    float* x3l   = big2 + 1024;   // x3[32][32]
    float* dec64 = big2;          // after x3 consumed
    float* dec128= big1;          // after Ag1 consumed

    int b = blockIdx.x, t = threadIdx.x;

    // P0: stage bits + di0
    for (int i = t; i < 2048; i += 256) bitsl[i] = packed[(size_t)b * 2048 + i];
    di0l[t] = di0g[b * NN + t];
    if (t < 32) gl[t] = wp[t];
    __syncthreads();

    // P1: z0 = di0 * (h @ W0) into big0 (stride 36) via TW gather
    for (int q = t; q < 2048; q += 256) {
        int node = q >> 3, cq = (q & 7) * 4;
        const int* xr = xa + (b * NN + node) * NF;
        float ax = 0.f, ay = 0.f, az = 0.f, aw = 0.f;
#pragma unroll
        for (int f = 0; f < NF; ++f) {
            int v = xr[f];
            const float4 tw = *reinterpret_cast<const float4*>(&TW[((f << 7) + v) * HC + cq]);
            ax += tw.x; ay += tw.y; az += tw.z; aw += tw.w;
        }
        float d = di0l[node];
        float* zp = &big0[node * 36 + cq];
        zp[0] = ax * d; zp[1] = ay * d; zp[2] = az * d; zp[3] = aw * d;
    }
    __syncthreads();

    // snorm level0
    float sn0 = 0.f;
    for (int i = 0; i < HC; ++i) { float v = gl[i]; sn0 += v * v; }
    sn0 = sqrtf(sn0);

    // P2: GCN0 (sparse bits) -> x0 to global, fused topk0 scores
    {
        int r0 = t >> 3, cq = (t & 7) * 4;
        for (int tile = 0; tile < 8; ++tile) {
            int r = tile * 32 + r0;
            float a0 = 0.f, a1 = 0.f, a2 = 0.f, a3 = 0.f;
#pragma unroll
            for (int w = 0; w < 8; ++w) {
                u32 m = bitsl[r * 8 + w];
                int base = w * 32;
                while (m) {
                    int j = base + __ffs(m) - 1;
                    m &= m - 1;
                    const float4 zv = *reinterpret_cast<const float4*>(&big0[j * 36 + cq]);
                    a0 += zv.x; a1 += zv.y; a2 += zv.z; a3 += zv.w;
                }
            }
            float dr = di0l[r];
            float o0 = fmaxf(dr * (a0 + 2.f * big0[r * 36 + cq + 0]) + bd0[cq + 0], 0.f);
            float o1 = fmaxf(dr * (a1 + 2.f * big0[r * 36 + cq + 1]) + bd0[cq + 1], 0.f);
            float o2 = fmaxf(dr * (a2 + 2.f * big0[r * 36 + cq + 2]) + bd0[cq + 2], 0.f);
            float o3 = fmaxf(dr * (a3 + 2.f * big0[r * 36 + cq + 3]) + bd0[cq + 3], 0.f);
            *reinterpret_cast<float4*>(&gx0[((size_t)b * NN + r) * HC + cq]) =
                make_float4(o0, o1, o2, o3);
            float pd = o0 * gl[cq] + o1 * gl[cq + 1] + o2 * gl[cq + 2] + o3 * gl[cq + 3];
            pd += __shfl_xor(pd, 1);
            pd += __shfl_xor(pd, 2);
            pd += __shfl_xor(pd, 4);
            if ((t & 7) == 0) scl[r] = tanhf(pd / sn0);
        }
    }
    __syncthreads();

    // P3: topk0 (256 -> 128)
    topk_sort<256, 128>(scl, keys, idx0l, vals0l, inv0l, t);

    // P4: gathered bits + popcount augment -> Ag0 in big0 (z0 dead)
    for (int i = t; i < 1024; i += 256) {
        int r = i >> 3, w = i & 7;
        int row = idx0l[r];
        u32 word = bitsl[row * 8 + w];
        if (w == (row >> 5)) word |= (1u << (row & 31));
        Pg[r * 9 + w] = word;
    }
    __syncthreads();
    {
        int rr0 = t >> 3, sb = (t & 7) * 4;
        u32 rw[8];
        for (int rt = 0; rt < 4; ++rt) {
            int r = rt * 32 + rr0;
#pragma unroll
            for (int w = 0; w < 8; ++w) rw[w] = Pg[r * 9 + w];
            for (int k4 = 0; k4 < 4; ++k4) {
                float4 res;
                float* rp = &res.x;
#pragma unroll
                for (int u = 0; u < 4; ++u) {
                    int s = sb + 32 * k4 + u;
                    int cnt = 0;
#pragma unroll
                    for (int w = 0; w < 8; ++w) cnt += __popc(rw[w] & Pg[s * 9 + w]);
                    rp[u] = (s == r) ? 0.f : (float)cnt;
                }
                *reinterpret_cast<float4*>(&big0[r * 128 + sb + 32 * k4]) = res;
            }
        }
    }
    __syncthreads();

    // P5: di1
    deg_lds<128>(big0, di1, t);

    // P6: level-0 GCN: xg = di1*vals0*x0[idx0] ; z = xg@Wd0 ; az -> x1
    for (int i = t; i < 1024; i += 256) Wl[(i >> 5) * 33 + (i & 31)] = wd[i];
    __syncthreads();
    for (int i = t; i < 4096; i += 256) {
        int r = i >> 5, c = i & 31;
        big1[i] = di1[r] * vals0l[r] * gx0[((size_t)b * NN + idx0l[r]) * HC + c];
    }
    __syncthreads();
    for (int i = t; i < 4096; i += 256) {
        int r = i >> 5, c = i & 31;
        float acc = 0.f;
#pragma unroll
        for (int e = 0; e < HC; ++e) acc += big1[r * 32 + e] * Wl[e * 33 + c];
        zb[r * 36 + c] = acc;
    }
    __syncthreads();
    az_dense<128>(big0, zb, di1, bd, x1l, t);

    // P7: topk1 (128 -> 64)
    if (t < 32) gl[t] = wp[32 + t];
    __syncthreads();
    {
        float sn = 0.f;
        for (int i = 0; i < HC; ++i) { float v = gl[i]; sn += v * v; }
        sn = sqrtf(sn);
        if (t < 128) {
            float acc = 0.f;
#pragma unroll
            for (int i = 0; i < HC; ++i) {
                int c = (i + t) & 31;
                acc += x1l[t * 32 + c] * gl[c];
            }
            scl[t] = tanhf(acc / sn);
        }
    }
    __syncthreads();
    topk_sort<128, 64>(scl, keys, idx1l, vals1l, inv1l, t);

    // P8: Ag1 in big1 (xg dead)
    aug_dense<128, 64>(big0, idx1l, big1, t);

    // P9: di2
    deg_lds<64>(big1, di2, t);

    // P10: level-1 GCN: xg in zb upper; z in zb; az -> x2
    for (int i = t; i < 1024; i += 256) Wl[(i >> 5) * 33 + (i & 31)] = wd[1024 + i];
    __syncthreads();
    {
        float* xg = zb + 2304;
        for (int i = t; i < 2048; i += 256) {
            int r = i >> 5, c = i & 31;
            xg[i] = di2[r] * vals1l[r] * x1l[idx1l[r] * 32 + c];
        }
        __syncthreads();
        for (int i = t; i < 2048; i += 256) {
            int r = i >> 5, c = i & 31;
            float acc = 0.f;
#pragma unroll
            for (int e = 0; e < HC; ++e) acc += xg[r * 32 + e] * Wl[e * 33 + c];
            zb[r * 36 + c] = acc;
        }
    }
    __syncthreads();
    az_dense<64>(big1, zb, di2, bd + 32, x2l, t);

    // P11: topk2 (64 -> 32)
    if (t < 32) gl[t] = wp[64 + t];
    __syncthreads();
    {
        float sn = 0.f;
        for (int i = 0; i < HC; ++i) { float v = gl[i]; sn += v * v; }
        sn = sqrtf(sn);
        if (t < 64) {
            float acc = 0.f;
#pragma unroll
            for (int i = 0; i < HC; ++i) {
                int c = (i + t) & 31;
                acc += x2l[t * 32 + c] * gl[c];
            }
            scl[t] = tanhf(acc / sn);
        }
    }
    __syncthreads();
    topk_sort<64, 32>(scl, keys, idx2l, vals2l, inv2l, t);

    // P12: Ag2 in big2[0..1024)
    aug_dense<64, 32>(big1, idx2l, big2, t);

    // P13: di3
    deg_lds<32>(big2, di3, t);

    // P14: level-2 GCN -> x3
    for (int i = t; i < 1024; i += 256) Wl[(i >> 5) * 33 + (i & 31)] = wd[2048 + i];
    __syncthreads();
    {
        float* xg = zb + 2304;
        for (int i = t; i < 1024; i += 256) {
            int r = i >> 5, c = i & 31;
            xg[i] = di3[r] * vals2l[r] * x2l[idx2l[r] * 32 + c];
        }
        __syncthreads();
        for (int i = t; i < 1024; i += 256) {
            int r = i >> 5, c = i & 31;
            float acc = 0.f;
#pragma unroll
            for (int e = 0; e < HC; ++e) acc += xg[r * 32 + e] * Wl[e * 33 + c];
            zb[r * 36 + c] = acc;
        }
    }
    __syncthreads();
    az_dense<32>(big2, zb, di3, bd + 64, x3l, t);

    // P15: decode0: x2 += scatter(x3, inv2); z = di2*(x2@Wu0); az(Ag1) -> dec64
    for (int i = t; i < 2048; i += 256) {
        int r = i >> 5, c = i & 31;
        int ir = inv2l[r];
        if (ir >= 0) x2l[i] += x3l[ir * 32 + c];
    }
    __syncthreads();
    for (int i = t; i < 1024; i += 256) Wl[(i >> 5) * 33 + (i & 31)] = wu[i];
    __syncthreads();
    for (int i = t; i < 2048; i += 256) {
        int r = i >> 5, c = i & 31;
        float acc = 0.f;
#pragma unroll
        for (int e = 0; e < HC; ++e) acc += x2l[r * 32 + e] * Wl[e * 33 + c];
        zb[r * 36 + c] = di2[r] * acc;
    }
    __syncthreads();
    az_dense<64>(big1, zb, di2, bu, dec64, t);

    // P16: decode1: x1 += scatter(dec64, inv1); z = di1*(x1@Wu1); az(Ag0) -> dec128
    for (int i = t; i < 4096; i += 256) {
        int r = i >> 5, c = i & 31;
        int ir = inv1l[r];
        if (ir >= 0) x1l[i] += dec64[ir * 32 + c];
    }
    __syncthreads();
    for (int i = t; i < 1024; i += 256) Wl[(i >> 5) * 33 + (i & 31)] = wu[1024 + i];
    __syncthreads();
    for (int i = t; i < 4096; i += 256) {
        int r = i >> 5, c = i & 31;
        float acc = 0.f;
#pragma unroll
        for (int e = 0; e < HC; ++e) acc += x1l[r * 32 + e] * Wl[e * 33 + c];
        zb[r * 36 + c] = di1[r] * acc;
    }
    __syncthreads();
    az_dense<128>(big0, zb, di1, bu + 32, dec128, t);

    // P17: final: s = An^T 1 (via bits); merge x0 + dec128; out = (sum_j s_j x_j) Wul + 256 b
    {
        float acc = 0.f;
        const u32* pr = &bitsl[t * 8];
#pragma unroll
        for (int w = 0; w < 8; ++w) {
            u32 m = pr[w];
            int base = w * 32;
            while (m) {
                int i = base + __ffs(m) - 1;
                m &= m - 1;
                acc += di0l[i];
            }
        }
        scl[t] = di0l[t] * (acc + 2.f * di0l[t]);   // sarr
    }
    __syncthreads();
    {
        int c = t & 31, jg = t >> 5;
        float a2 = 0.f;
        for (int j = jg * 32; j < jg * 32 + 32; ++j) {
            int ir = inv0l[j];
            float xv = gx0[((size_t)b * NN + j) * HC + c];
            if (ir >= 0) xv += dec128[ir * 32 + c];
            a2 += scl[j] * xv;
        }
        part[jg * 33 + c] = a2;
    }
    __syncthreads();
    if (t < HC) {
        float g = 0.f;
        for (int q = 0; q < 8; ++q) g += part[q * 33 + t];
        gl[t] = g;
    }
    __syncthreads();
    float a3 = 0.f;
    for (int cc = 0; cc < HC; ++cc) a3 += gl[cc] * wul[cc * EMBD + t];
    outp[b * EMBD + t] = a3 + 256.0f * bul[t];
}

// ---------------------------------------------------------------------------
extern "C" void kernel_launch(void* const* d_in, const int* in_sizes, int n_in,
                              void* d_out, int out_size, void* d_ws, size_t ws_size,
                              hipStream_t stream) {
    const float* adj       = (const float*)d_in[0];
    const int*   xatom     = (const int*)d_in[1];
    const float* table     = (const float*)d_in[2];
    const float* w_down0   = (const float*)d_in[3];
    const float* b_down0   = (const float*)d_in[4];
    const float* w_down    = (const float*)d_in[5];
    const float* b_down    = (const float*)d_in[6];
    const float* w_pool    = (const float*)d_in[7];
    const float* w_up      = (const float*)d_in[8];
    const float* b_up      = (const float*)d_in[9];
    const float* w_up_last = (const float*)d_in[10];
    const float* b_up_last = (const float*)d_in[11];
    float* outp = (float*)d_out;

    float* ws = (float*)d_ws;
    size_t off = 0;
    auto alloc = [&](size_t nf) {
        float* p = ws + off;
        off += (nf + 63) & ~((size_t)63);
        return p;
    };
    u32*   packed = (u32*)alloc((size_t)NB * NN * 8);
    float* di0g   = alloc(NB * NN);
    float* TW     = alloc(NF * NV * HC);
    float* gx0    = alloc((size_t)NB * NN * HC);

    k_pack<<<NB * 64, 256, 0, stream>>>(adj, packed, di0g);
    k_tw<<<(NF * NV * HC + 255) / 256, 256, 0, stream>>>(table, w_down0, TW);
    k_mega<<<NB, 256, 0, stream>>>(packed, di0g, TW, xatom,
                                   b_down0, w_down, b_down, w_pool,
                                   w_up, b_up, w_up_last, b_up_last,
                                   gx0, outp);
}

// Round 5
// 127.583 us; speedup vs baseline: 4.7584x; 1.3402x over previous
//
#include <hip/hip_runtime.h>
#include <stdint.h>
#include <math.h>

#define NB 256      // graphs (B)
#define NN 256      // nodes at level 0
#define HC 32       // hidden channels
#define EMBD 256    // embedding dim
#define NF 9        // atom feat cols
#define NV 128      // padded vocab

typedef unsigned int u32;
typedef unsigned long long u64;

// ---------------------------------------------------------------------------
// TW[f,v,c] = sum_e table[f,v,e] * W0[e,c]
__global__ void k_tw(const float* __restrict__ table, const float* __restrict__ W0,
                     float* __restrict__ TW) {
    int gid = blockIdx.x * 256 + threadIdx.x;
    if (gid >= NF * NV * HC) return;
    int c = gid & 31;
    int v = (gid >> 5) & (NV - 1);
    int f = gid >> 12;
    const float* trow = table + (size_t)(f * NV + v) * EMBD;
    float acc = 0.f;
    for (int e = 0; e < EMBD; ++e) acc += trow[e] * W0[e * HC + c];
    TW[gid] = acc;
}

// ---------------------------------------------------------------------------
// LDS layout (byte offsets), total 134208 <= 160 KiB
#define SM_BITS   0        // u32[2048]
#define SM_DI0    8192     // f[256]
#define SM_BIG0   9216     // z0raw stride36 (36KB) -> Ag0 u8[128*128] (16KB)
#define SM_X1     46080    // f[128*36]
#define SM_BIG1   64512    // f[4608]: xg0 / Ag1 f32[64*64] / dec128[128*36]
#define SM_X2     82944    // f[64*36]
#define SM_BIG2   92160    // f[2304]: Ag2[1024] + x3@+1024; dec64[64*36]
#define SM_ZB     101376   // f[4608]: z stride36; xg@+2304; Gb u32[64*33]
#define SM_WG     119808   // Pg u32[128*9] / Wl f[32*36]  (4608B)
#define SM_SC     124416   // f[256]
#define SM_KEYS   125440   // u64[256]
#define SM_IDX0   127488
#define SM_VALS0  128000
#define SM_INV0   128512
#define SM_IDX1   129536
#define SM_VALS1  129792
#define SM_INV1   130048
#define SM_IDX2   130560
#define SM_VALS2  130688
#define SM_INV2   130816
#define SM_DI1    131072
#define SM_DI2    131584
#define SM_DI3    131840
#define SM_PART   131968   // f[528]
#define SM_GL     134080   // f[32]
#define SM_TOTAL  134208

__device__ __forceinline__ u32 dot4acc(u32 a, u32 b, u32 c) {
#if __has_builtin(__builtin_amdgcn_udot4)
    return __builtin_amdgcn_udot4(a, b, c, false);
#else
    return c + (a & 0xffu) * (b & 0xffu) + ((a >> 8) & 0xffu) * ((b >> 8) & 0xffu)
         + ((a >> 16) & 0xffu) * ((b >> 16) & 0xffu) + (a >> 24) * (b >> 24);
#endif
}

// Bitonic top-k: sc[0..N) -> idx/vals[0..K), inv[0..N). Desc score, asc index.
template <int N, int K>
__device__ __forceinline__ void topk_sort(const float* sc, u64* keys,
                                          int* idxo, float* valso, int* invo, int t) {
    if (t < N) {
        invo[t] = -1;
        float s = sc[t];
        u32 bits = __float_as_uint(s);
        u32 m = ((int)bits < 0) ? 0xFFFFFFFFu : 0x80000000u;
        u32 ordv = ~(bits ^ m);
        keys[t] = ((u64)ordv << 32) | (u32)t;
    }
    __syncthreads();
    for (int size = 2; size <= N; size <<= 1)
        for (int stride = size >> 1; stride > 0; stride >>= 1) {
            if (t < N) {
                int j = t ^ stride;
                if (j > t) {
                    bool asc = ((t & size) == 0);
                    u64 ka = keys[t], kb = keys[j];
                    if ((ka > kb) == asc) { keys[t] = kb; keys[j] = ka; }
                }
            }
            __syncthreads();
        }
    if (t < K) {
        int id = (int)(keys[t] & 0xFFFFFFFFu);
        idxo[t] = id;
        valso[t] = sc[id];
        invo[id] = t;
    }
    __syncthreads();
}

// Dense GCN (f32 A, symmetric, stride N): j-outer broadcast, RPT rows/thread.
template <int N, int RPT>
__device__ __forceinline__ void az_f32(const float* A, const float* z,
                                       const float* di, const float* __restrict__ bias,
                                       float* xout, int t) {
    constexpr int ACT = (N / RPT) * 8;
    if (t < ACT) {
        int rg = t >> 3, cq = (t & 7) * 4;
        float ax[RPT][4];
#pragma unroll
        for (int i = 0; i < RPT; ++i) { ax[i][0] = ax[i][1] = ax[i][2] = ax[i][3] = 0.f; }
        for (int jj = 0; jj < N; ++jj) {
            const float4 zv = *reinterpret_cast<const float4*>(&z[jj * 36 + cq]);
#pragma unroll
            for (int i = 0; i < RPT; ++i) {
                float a = A[jj * N + rg * RPT + i];
                ax[i][0] += a * zv.x; ax[i][1] += a * zv.y;
                ax[i][2] += a * zv.z; ax[i][3] += a * zv.w;
            }
        }
#pragma unroll
        for (int i = 0; i < RPT; ++i) {
            int r = rg * RPT + i;
            float dr = di[r];
            float4 o;
            o.x = fmaxf(dr * (ax[i][0] + 2.f * z[r * 36 + cq + 0]) + bias[cq + 0], 0.f);
            o.y = fmaxf(dr * (ax[i][1] + 2.f * z[r * 36 + cq + 1]) + bias[cq + 1], 0.f);
            o.z = fmaxf(dr * (ax[i][2] + 2.f * z[r * 36 + cq + 2]) + bias[cq + 2], 0.f);
            o.w = fmaxf(dr * (ax[i][3] + 2.f * z[r * 36 + cq + 3]) + bias[cq + 3], 0.f);
            *reinterpret_cast<float4*>(&xout[r * 36 + cq]) = o;
        }
    }
    __syncthreads();
}

// Dense GCN over u8 A (128x128, zero diag): 1 u32 = 4 row values per jj.
__device__ __forceinline__ void az_u8(const u32* AgW, const float* z,
                                      const float* di, const float* __restrict__ bias,
                                      float* xout, int t) {
    if (t < 256) {
        int rg = t >> 3, cq = (t & 7) * 4;
        float ax[4][4];
#pragma unroll
        for (int i = 0; i < 4; ++i) { ax[i][0] = ax[i][1] = ax[i][2] = ax[i][3] = 0.f; }
        for (int jj = 0; jj < 128; ++jj) {
            const float4 zv = *reinterpret_cast<const float4*>(&z[jj * 36 + cq]);
            u32 w = AgW[jj * 32 + rg];
            float f0 = (float)(w & 255u), f1 = (float)((w >> 8) & 255u);
            float f2 = (float)((w >> 16) & 255u), f3 = (float)(w >> 24);
            ax[0][0] += f0 * zv.x; ax[0][1] += f0 * zv.y; ax[0][2] += f0 * zv.z; ax[0][3] += f0 * zv.w;
            ax[1][0] += f1 * zv.x; ax[1][1] += f1 * zv.y; ax[1][2] += f1 * zv.z; ax[1][3] += f1 * zv.w;
            ax[2][0] += f2 * zv.x; ax[2][1] += f2 * zv.y; ax[2][2] += f2 * zv.z; ax[2][3] += f2 * zv.w;
            ax[3][0] += f3 * zv.x; ax[3][1] += f3 * zv.y; ax[3][2] += f3 * zv.z; ax[3][3] += f3 * zv.w;
        }
#pragma unroll
        for (int i = 0; i < 4; ++i) {
            int r = rg * 4 + i;
            float dr = di[r];
            float4 o;
            o.x = fmaxf(dr * (ax[i][0] + 2.f * z[r * 36 + cq + 0]) + bias[cq + 0], 0.f);
            o.y = fmaxf(dr * (ax[i][1] + 2.f * z[r * 36 + cq + 1]) + bias[cq + 1], 0.f);
            o.z = fmaxf(dr * (ax[i][2] + 2.f * z[r * 36 + cq + 2]) + bias[cq + 2], 0.f);
            o.w = fmaxf(dr * (ax[i][3] + 2.f * z[r * 36 + cq + 3]) + bias[cq + 3], 0.f);
            *reinterpret_cast<float4*>(&xout[r * 36 + cq]) = o;
        }
    }
    __syncthreads();
}

// z[r,:] (stride36) = pre[r] * xin[r,:] @ Wl  (xin stride 36, Wl stride 36)
template <int N>
__device__ __forceinline__ void xw_mm(const float* xin, const float* Wl,
                                      const float* pre, float* zout, int t) {
    for (int i = t; i < N * 8; i += 512) {
        int r = i >> 3, cq = (i & 7) * 4;
        float a0 = 0.f, a1 = 0.f, a2 = 0.f, a3 = 0.f;
#pragma unroll 8
        for (int e = 0; e < 32; ++e) {
            float xv = xin[r * 36 + e];
            const float4 wv = *reinterpret_cast<const float4*>(&Wl[e * 36 + cq]);
            a0 += xv * wv.x; a1 += xv * wv.y; a2 += xv * wv.z; a3 += xv * wv.w;
        }
        float p = pre ? pre[r] : 1.f;
        *reinterpret_cast<float4*>(&zout[r * 36 + cq]) =
            make_float4(a0 * p, a1 * p, a2 * p, a3 * p);
    }
    __syncthreads();
}

// col sums of symmetric f32 NxN -> di = 1/sqrt(sum+2)
template <int N>
__device__ __forceinline__ void deg_lds(const float* A, float* di, int t) {
    if (t < N) {
        float acc = 0.f;
        for (int i = 0; i < N; ++i) acc += A[i * N + t];
        di[t] = 1.0f / sqrtf(acc + 2.0f);
    }
    __syncthreads();
}

// row sums of u8 128x128 -> di1
__device__ __forceinline__ void deg_u8(const u32* AgW, float* di, int t) {
    if (t < 128) {
        u32 acc = 0;
        for (int w = 0; w < 32; ++w)
            acc = dot4acc(AgW[t * 32 + ((w + t) & 31)], 0x01010101u, acc);
        di[t] = 1.0f / sqrtf((float)acc + 2.0f);
    }
    __syncthreads();
}

// Ag2[32x32] = gathered augment of Ag1 (f32 64x64, zero diag, symmetric)
__device__ __forceinline__ void aug64_32(const float* A, const int* idxl,
                                         float* out, int t) {
    if (t < 256) {
        int rr0 = t >> 3, sb = (t & 7) * 4;
        int ir = idxl[rr0];
        int is0 = idxl[sb], is1 = idxl[sb + 1], is2 = idxl[sb + 2], is3 = idxl[sb + 3];
        float c0 = 0.f, c1 = 0.f, c2 = 0.f, c3 = 0.f;
        for (int jj = 0; jj < 16; ++jj) {
            int jq = ((jj + rr0) & 15) * 4;
            const float4 ar = *reinterpret_cast<const float4*>(&A[ir * 64 + jq]);
            const float4 v0 = *reinterpret_cast<const float4*>(&A[is0 * 64 + jq]);
            const float4 v1 = *reinterpret_cast<const float4*>(&A[is1 * 64 + jq]);
            const float4 v2 = *reinterpret_cast<const float4*>(&A[is2 * 64 + jq]);
            const float4 v3 = *reinterpret_cast<const float4*>(&A[is3 * 64 + jq]);
            c0 += ar.x * v0.x + ar.y * v0.y + ar.z * v0.z + ar.w * v0.w;
            c1 += ar.x * v1.x + ar.y * v1.y + ar.z * v1.z + ar.w * v1.w;
            c2 += ar.x * v2.x + ar.y * v2.y + ar.z * v2.z + ar.w * v2.w;
            c3 += ar.x * v3.x + ar.y * v3.y + ar.z * v3.z + ar.w * v3.w;
        }
        float o0 = c0 + 2.f * A[ir * 64 + is0] + (ir == is0 ? 1.f : 0.f);
        float o1 = c1 + 2.f * A[ir * 64 + is1] + (ir == is1 ? 1.f : 0.f);
        float o2 = c2 + 2.f * A[ir * 64 + is2] + (ir == is2 ? 1.f : 0.f);
        float o3 = c3 + 2.f * A[ir * 64 + is3] + (ir == is3 ? 1.f : 0.f);
        if (rr0 == sb + 0) o0 = 0.f;
        if (rr0 == sb + 1) o1 = 0.f;
        if (rr0 == sb + 2) o2 = 0.f;
        if (rr0 == sb + 3) o3 = 0.f;
        *reinterpret_cast<float4*>(&out[rr0 * 32 + sb]) = make_float4(o0, o1, o2, o3);
    }
    __syncthreads();
}

// ---------------------------------------------------------------------------
__global__ void __launch_bounds__(512, 1) k_mega(
    const float* __restrict__ adj, const float* __restrict__ TW,
    const int* __restrict__ xa,
    const float* __restrict__ bd0, const float* __restrict__ wd,
    const float* __restrict__ bd, const float* __restrict__ wp,
    const float* __restrict__ wu, const float* __restrict__ bu,
    const float* __restrict__ wul, const float* __restrict__ bul,
    float* __restrict__ gx0, float* __restrict__ outp) {
    __shared__ __align__(16) char SM[SM_TOTAL];
    u32*   bitsl = (u32*)(SM + SM_BITS);
    float* di0l  = (float*)(SM + SM_DI0);
    float* z0    = (float*)(SM + SM_BIG0);
    u32*   AgW   = (u32*)(SM + SM_BIG0);
    float* x1l   = (float*)(SM + SM_X1);
    float* big1  = (float*)(SM + SM_BIG1);   // xg0 / Ag1 / dec128
    float* x2l   = (float*)(SM + SM_X2);
    float* big2  = (float*)(SM + SM_BIG2);   // Ag2 / x3 / dec64
    float* zbf   = (float*)(SM + SM_ZB);
    u32*   Pg    = (u32*)(SM + SM_WG);
    float* Wl    = (float*)(SM + SM_WG);
    float* scl   = (float*)(SM + SM_SC);
    u64*   keys  = (u64*)(SM + SM_KEYS);
    int*   idx0l = (int*)(SM + SM_IDX0);
    float* vals0l= (float*)(SM + SM_VALS0);
    int*   inv0l = (int*)(SM + SM_INV0);
    int*   idx1l = (int*)(SM + SM_IDX1);
    float* vals1l= (float*)(SM + SM_VALS1);
    int*   inv1l = (int*)(SM + SM_INV1);
    int*   idx2l = (int*)(SM + SM_IDX2);
    float* vals2l= (float*)(SM + SM_VALS2);
    int*   inv2l = (int*)(SM + SM_INV2);
    float* di1   = (float*)(SM + SM_DI1);
    float* di2   = (float*)(SM + SM_DI2);
    float* di3   = (float*)(SM + SM_DI3);
    float* part  = (float*)(SM + SM_PART);
    float* gl    = (float*)(SM + SM_GL);
    float* x3l   = big2 + 1024;
    float* dec64 = big2;
    float* dec128= big1;

    int b = blockIdx.x, t = threadIdx.x;

    // P1: z0raw = h @ W0 via TW gather (independent of adjacency)
    for (int i = t; i < 2048; i += 512) {
        int node = i >> 3, cq = (i & 7) * 4;
        const int* xr = xa + (b * NN + node) * NF;
        float ax = 0.f, ay = 0.f, azz = 0.f, aw = 0.f;
#pragma unroll
        for (int f = 0; f < NF; ++f) {
            int v = xr[f];
            const float4 tw = *reinterpret_cast<const float4*>(&TW[((f << 7) + v) * HC + cq]);
            ax += tw.x; ay += tw.y; azz += tw.z; aw += tw.w;
        }
        *reinterpret_cast<float4*>(&z0[node * 36 + cq]) = make_float4(ax, ay, azz, aw);
    }

    // P0: pack adjacency + di0 (fused, per-wave ballot)
    {
        int lane = t & 63, wv = t >> 6;
        for (int row = wv; row < NN; row += 8) {
            const float* ar = adj + ((size_t)b * NN + row) * NN;
            int deg = 0;
#pragma unroll
            for (int p = 0; p < 4; ++p) {
                u64 m = __ballot(ar[p * 64 + lane] != 0.0f);
                if (lane == 0) {
                    bitsl[row * 8 + 2 * p]     = (u32)m;
                    bitsl[row * 8 + 2 * p + 1] = (u32)(m >> 32);
                    deg += __popcll(m);
                }
            }
            if (lane == 0) di0l[row] = 1.0f / sqrtf((float)deg + 2.0f);
        }
    }
    if (t < 32) gl[t] = wp[t];
    __syncthreads();

    // P2: GCN0 sparse (bits), di0 folded into FMA; fused topk0 scores; x0 -> global
    {
        float sn0 = 0.f;
        for (int i = 0; i < HC; ++i) { float v = gl[i]; sn0 += v * v; }
        sn0 = sqrtf(sn0);
        int r0 = t >> 3, cq = (t & 7) * 4;
        for (int tile = 0; tile < 4; ++tile) {
            int r = tile * 64 + r0;
            float a0 = 0.f, a1 = 0.f, a2 = 0.f, a3 = 0.f;
#pragma unroll
            for (int w = 0; w < 8; ++w) {
                u32 m = bitsl[r * 8 + w];
                int base = w * 32;
                while (m) {
                    int j = base + __ffs(m) - 1;
                    m &= m - 1;
                    float dj = di0l[j];
                    const float4 zv = *reinterpret_cast<const float4*>(&z0[j * 36 + cq]);
                    a0 += dj * zv.x; a1 += dj * zv.y; a2 += dj * zv.z; a3 += dj * zv.w;
                }
            }
            float dr = di0l[r];
            float o0 = fmaxf(dr * (a0 + 2.f * dr * z0[r * 36 + cq + 0]) + bd0[cq + 0], 0.f);
            float o1 = fmaxf(dr * (a1 + 2.f * dr * z0[r * 36 + cq + 1]) + bd0[cq + 1], 0.f);
            float o2 = fmaxf(dr * (a2 + 2.f * dr * z0[r * 36 + cq + 2]) + bd0[cq + 2], 0.f);
            float o3 = fmaxf(dr * (a3 + 2.f * dr * z0[r * 36 + cq + 3]) + bd0[cq + 3], 0.f);
            *reinterpret_cast<float4*>(&gx0[((size_t)b * NN + r) * HC + cq]) =
                make_float4(o0, o1, o2, o3);
            float pd = o0 * gl[cq] + o1 * gl[cq + 1] + o2 * gl[cq + 2] + o3 * gl[cq + 3];
            pd += __shfl_xor(pd, 1);
            pd += __shfl_xor(pd, 2);
            pd += __shfl_xor(pd, 4);
            if ((t & 7) == 0) scl[r] = tanhf(pd / sn0);
        }
    }
    __syncthreads();

    // P3: topk0 256->128
    topk_sort<256, 128>(scl, keys, idx0l, vals0l, inv0l, t);

    // P4: gathered bits -> popcount augment -> Ag0 u8 (z0 dead)
    for (int i = t; i < 1024; i += 512) {
        int r = i >> 3, w = i & 7;
        int row = idx0l[r];
        u32 word = bitsl[row * 8 + w];
        if (w == (row >> 5)) word |= (1u << (row & 31));
        Pg[r * 9 + w] = word;
    }
    __syncthreads();
    {
        int rr0 = t >> 4, sb = (t & 15) * 4;
        u32 rw[4][8];
#pragma unroll
        for (int rt = 0; rt < 4; ++rt)
#pragma unroll
            for (int w = 0; w < 8; ++w) rw[rt][w] = Pg[(rt * 32 + rr0) * 9 + w];
#pragma unroll
        for (int k4 = 0; k4 < 2; ++k4) {
            int s0 = sb + 64 * k4;
            u32 cnt[4][4];
#pragma unroll
            for (int a = 0; a < 4; ++a) { cnt[a][0] = cnt[a][1] = cnt[a][2] = cnt[a][3] = 0; }
#pragma unroll
            for (int u = 0; u < 4; ++u) {
                int s = s0 + u;
#pragma unroll
                for (int w = 0; w < 8; ++w) {
                    u32 sw = Pg[s * 9 + w];
                    cnt[0][u] += __popc(rw[0][w] & sw);
                    cnt[1][u] += __popc(rw[1][w] & sw);
                    cnt[2][u] += __popc(rw[2][w] & sw);
                    cnt[3][u] += __popc(rw[3][w] & sw);
                }
            }
#pragma unroll
            for (int rt = 0; rt < 4; ++rt) {
                int r = rt * 32 + rr0;
                if (r >= s0 && r < s0 + 4) cnt[rt][r - s0] = 0;
                AgW[r * 32 + (s0 >> 2)] =
                    cnt[rt][0] | (cnt[rt][1] << 8) | (cnt[rt][2] << 16) | (cnt[rt][3] << 24);
            }
        }
    }
    __syncthreads();

    // P5: di1 from u8 row sums
    deg_u8(AgW, di1, t);

    // P6: level-0 GCN: xg = di1*vals0*x0[idx0]; z = xg@Wd0; az(Ag0u8) -> x1
    for (int i = t; i < 1024; i += 512) Wl[(i >> 5) * 36 + (i & 31)] = wd[i];
    for (int i = t; i < 1024; i += 512) {
        int r = i >> 3, cq = (i & 7) * 4;
        float s = di1[r] * vals0l[r];
        const float4 xv = *reinterpret_cast<const float4*>(
            &gx0[((size_t)b * NN + idx0l[r]) * HC + cq]);
        *reinterpret_cast<float4*>(&big1[r * 36 + cq]) =
            make_float4(s * xv.x, s * xv.y, s * xv.z, s * xv.w);
    }
    __syncthreads();
    xw_mm<128>(big1, Wl, nullptr, zbf, t);
    az_u8(AgW, zbf, di1, bd, x1l, t);

    // P7: topk1 128->64
    if (t < 32) gl[t] = wp[32 + t];
    __syncthreads();
    {
        float sn = 0.f;
        for (int i = 0; i < HC; ++i) { float v = gl[i]; sn += v * v; }
        sn = sqrtf(sn);
        if (t < 128) {
            float acc = 0.f;
#pragma unroll
            for (int i = 0; i < HC; ++i) {
                int c = (i + t) & 31;
                acc += x1l[t * 36 + c] * gl[c];
            }
            scl[t] = tanhf(acc / sn);
        }
    }
    __syncthreads();
    topk_sort<128, 64>(scl, keys, idx1l, vals1l, inv1l, t);

    // P8: Ag1 via u8 dot4: stage gathered byte-rows (diag baked), udot4 16 per thread
    {
        u32* Gb = (u32*)zbf;
        for (int i = t; i < 2048; i += 512) {
            int k = i >> 5, w = i & 31;
            int ir = idx1l[k];
            u32 word = AgW[ir * 32 + w];
            if (w == (ir >> 2)) word += (1u << (8 * (ir & 3)));
            Gb[k * 33 + w] = word;
        }
        __syncthreads();
        if (t < 256) {
            int rq = t >> 4, sq = t & 15;
            u32 racc[4][4];
#pragma unroll
            for (int a = 0; a < 4; ++a) { racc[a][0] = racc[a][1] = racc[a][2] = racc[a][3] = 0; }
            for (int w = 0; w < 32; ++w) {
                u32 rv0 = Gb[(rq * 4 + 0) * 33 + w], rv1 = Gb[(rq * 4 + 1) * 33 + w];
                u32 rv2 = Gb[(rq * 4 + 2) * 33 + w], rv3 = Gb[(rq * 4 + 3) * 33 + w];
                u32 sv0 = Gb[(sq * 4 + 0) * 33 + w], sv1 = Gb[(sq * 4 + 1) * 33 + w];
                u32 sv2 = Gb[(sq * 4 + 2) * 33 + w], sv3 = Gb[(sq * 4 + 3) * 33 + w];
                racc[0][0] = dot4acc(rv0, sv0, racc[0][0]); racc[0][1] = dot4acc(rv0, sv1, racc[0][1]);
                racc[0][2] = dot4acc(rv0, sv2, racc[0][2]); racc[0][3] = dot4acc(rv0, sv3, racc[0][3]);
                racc[1][0] = dot4acc(rv1, sv0, racc[1][0]); racc[1][1] = dot4acc(rv1, sv1, racc[1][1]);
                racc[1][2] = dot4acc(rv1, sv2, racc[1][2]); racc[1][3] = dot4acc(rv1, sv3, racc[1][3]);
                racc[2][0] = dot4acc(rv2, sv0, racc[2][0]); racc[2][1] = dot4acc(rv2, sv1, racc[2][1]);
                racc[2][2] = dot4acc(rv2, sv2, racc[2][2]); racc[2][3] = dot4acc(rv2, sv3, racc[2][3]);
                racc[3][0] = dot4acc(rv3, sv0, racc[3][0]); racc[3][1] = dot4acc(rv3, sv1, racc[3][1]);
                racc[3][2] = dot4acc(rv3, sv2, racc[3][2]); racc[3][3] = dot4acc(rv3, sv3, racc[3][3]);
            }
#pragma unroll
            for (int i = 0; i < 4; ++i) {
                int r = rq * 4 + i;
                float4 o;
                o.x = (r == sq * 4 + 0) ? 0.f : (float)racc[i][0];
                o.y = (r == sq * 4 + 1) ? 0.f : (float)racc[i][1];
                o.z = (r == sq * 4 + 2) ? 0.f : (float)racc[i][2];
                o.w = (r == sq * 4 + 3) ? 0.f : (float)racc[i][3];
                *reinterpret_cast<float4*>(&big1[r * 64 + sq * 4]) = o;
            }
        }
        __syncthreads();
    }

    // P9: di2
    deg_lds<64>(big1, di2, t);

    // P10: level-1 GCN -> x2
    for (int i = t; i < 1024; i += 512) Wl[(i >> 5) * 36 + (i & 31)] = wd[1024 + i];
    {
        float* xg1 = zbf + 2304;
        int r = t >> 3, cq = (t & 7) * 4;
        float s = di2[r] * vals1l[r];
        const float4 xv = *reinterpret_cast<const float4*>(&x1l[idx1l[r] * 36 + cq]);
        *reinterpret_cast<float4*>(&xg1[r * 36 + cq]) =
            make_float4(s * xv.x, s * xv.y, s * xv.z, s * xv.w);
    }
    __syncthreads();
    xw_mm<64>(zbf + 2304, Wl, nullptr, zbf, t);
    az_f32<64, 2>(big1, zbf, di2, bd + 32, x2l, t);

    // P11: topk2 64->32
    if (t < 32) gl[t] = wp[64 + t];
    __syncthreads();
    {
        float sn = 0.f;
        for (int i = 0; i < HC; ++i) { float v = gl[i]; sn += v * v; }
        sn = sqrtf(sn);
        if (t < 64) {
            float acc = 0.f;
#pragma unroll
            for (int i = 0; i < HC; ++i) {
                int c = (i + t) & 31;
                acc += x2l[t * 36 + c] * gl[c];
            }
            scl[t] = tanhf(acc / sn);
        }
    }
    __syncthreads();
    topk_sort<64, 32>(scl, keys, idx2l, vals2l, inv2l, t);

    // P12: Ag2
    aug64_32(big1, idx2l, big2, t);

    // P13: di3
    deg_lds<32>(big2, di3, t);

    // P14: level-2 GCN -> x3
    for (int i = t; i < 1024; i += 512) Wl[(i >> 5) * 36 + (i & 31)] = wd[2048 + i];
    if (t < 256) {
        float* xg2 = zbf + 2304;
        int r = t >> 3, cq = (t & 7) * 4;
        float s = di3[r] * vals2l[r];
        const float4 xv = *reinterpret_cast<const float4*>(&x2l[idx2l[r] * 36 + cq]);
        *reinterpret_cast<float4*>(&xg2[r * 36 + cq]) =
            make_float4(s * xv.x, s * xv.y, s * xv.z, s * xv.w);
    }
    __syncthreads();
    xw_mm<32>(zbf + 2304, Wl, nullptr, zbf, t);
    az_f32<32, 2>(big2, zbf, di3, bd + 64, x3l, t);

    // P15: decode0: x2 += scatter(x3, inv2); z = di2*(x2@Wu0); az(Ag1) -> dec64
    for (int i = t; i < 2048; i += 512) {
        int r = i >> 5, c = i & 31;
        int ir = inv2l[r];
        if (ir >= 0) x2l[r * 36 + c] += x3l[ir * 36 + c];
    }
    for (int i = t; i < 1024; i += 512) Wl[(i >> 5) * 36 + (i & 31)] = wu[i];
    __syncthreads();
    xw_mm<64>(x2l, Wl, di2, zbf, t);
    az_f32<64, 2>(big1, zbf, di2, bu, dec64, t);

    // P16: decode1: x1 += scatter(dec64, inv1); z = di1*(x1@Wu1); az(Ag0u8) -> dec128
    for (int i = t; i < 4096; i += 512) {
        int r = i >> 5, c = i & 31;
        int ir = inv1l[r];
        if (ir >= 0) x1l[r * 36 + c] += dec64[ir * 36 + c];
    }
    for (int i = t; i < 1024; i += 512) Wl[(i >> 5) * 36 + (i & 31)] = wu[1024 + i];
    __syncthreads();
    xw_mm<128>(x1l, Wl, di1, zbf, t);
    az_u8(AgW, zbf, di1, bu + 32, dec128, t);

    // P17: final GCN (bits) + merge + global_add_pool + out matvec
    if (t < 256) {
        float acc = 0.f;
        const u32* pr = &bitsl[t * 8];
#pragma unroll
        for (int w = 0; w < 8; ++w) {
            u32 m = pr[w];
            int base = w * 32;
            while (m) {
                int i = base + __ffs(m) - 1;
                m &= m - 1;
                acc += di0l[i];
            }
        }
        scl[t] = di0l[t] * (acc + 2.f * di0l[t]);
    }
    __syncthreads();
    {
        int c = t & 31, jg = t >> 5;
        float a2 = 0.f;
        for (int j = jg * 16; j < jg * 16 + 16; ++j) {
            int ir = inv0l[j];
            float xv = gx0[((size_t)b * NN + j) * HC + c];
            if (ir >= 0) xv += dec128[ir * 36 + c];
            a2 += scl[j] * xv;
        }
        part[jg * 33 + c] = a2;
    }
    __syncthreads();
    if (t < 32) {
        float g = 0.f;
#pragma unroll
        for (int q = 0; q < 16; ++q) g += part[q * 33 + t];
        gl[t] = g;
    }
    __syncthreads();
    if (t < 256) {
        float a3 = 0.f;
#pragma unroll
        for (int cc = 0; cc < HC; ++cc) a3 += gl[cc] * wul[cc * EMBD + t];
        outp[b * EMBD + t] = a3 + 256.0f * bul[t];
    }
}

// ---------------------------------------------------------------------------
extern "C" void kernel_launch(void* const* d_in, const int* in_sizes, int n_in,
                              void* d_out, int out_size, void* d_ws, size_t ws_size,
                              hipStream_t stream) {
    const float* adj       = (const float*)d_in[0];
    const int*   xatom     = (const int*)d_in[1];
    const float* table     = (const float*)d_in[2];
    const float* w_down0   = (const float*)d_in[3];
    const float* b_down0   = (const float*)d_in[4];
    const float* w_down    = (const float*)d_in[5];
    const float* b_down    = (const float*)d_in[6];
    const float* w_pool    = (const float*)d_in[7];
    const float* w_up      = (const float*)d_in[8];
    const float* b_up      = (const float*)d_in[9];
    const float* w_up_last = (const float*)d_in[10];
    const float* b_up_last = (const float*)d_in[11];
    float* outp = (float*)d_out;

    float* ws = (float*)d_ws;
    float* TW  = ws;                       // 9*128*32 = 36864 f
    float* gx0 = ws + 36928;               // 256*256*32 = 2097152 f

    k_tw<<<(NF * NV * HC + 255) / 256, 256, 0, stream>>>(table, w_down0, TW);
    k_mega<<<NB, 512, 0, stream>>>(adj, TW, xatom,
                                   b_down0, w_down, b_down, w_pool,
                                   w_up, b_up, w_up_last, b_up_last,
                                   gx0, outp);
}